// Round 1
// baseline (846.154 us; speedup 1.0000x reference)
//
#include <hip/hip_runtime.h>

// Problem constants
#define BB 16
#define NN 4096
#define MM 1024
#define C1V 128
#define C2V 256
#define KIN 384      // C1+C2
#define O1 256       // MLP0
#define O2 256       // MLP1
#define RTOT (BB*NN) // 65536 rows
#define EPSV 1e-5f
#define INV_CNT (1.0f/65536.0f)

// GEMM tiling
#define BM 64
#define BN 64
#define BK 32
#define LDA 65  // padded leading dim for LDS tiles (conflict-free)

// ---------------------------------------------------------------------------
// Kernel 1: 3-NN search + inverse-distance weights.
// One block per (batch, 256-point tile). xyz2 for the batch staged in LDS.
// ---------------------------------------------------------------------------
__global__ __launch_bounds__(256) void knn_kernel(
    const float* __restrict__ xyz1, const float* __restrict__ xyz2,
    float* __restrict__ w_out, int* __restrict__ i_out) {
  __shared__ float sx[MM], sy[MM], sz[MM];
  int b = blockIdx.x >> 4;      // 16 tiles of 256 points per batch
  int tile = blockIdx.x & 15;
  int t = threadIdx.x;
  const float* x2b = xyz2 + b * 3 * MM;   // (3, M) for this batch
  for (int i = 0; i < 12; ++i) {          // 3072 floats / 256 threads
    int e = i * 256 + t;
    float v = x2b[e];
    int coord = e >> 10, m = e & 1023;
    float* dst = (coord == 0) ? sx : (coord == 1) ? sy : sz;
    dst[m] = v;
  }
  __syncthreads();

  int n = tile * 256 + t;
  const float* x1b = xyz1 + b * 3 * NN;
  float px = x1b[n], py = x1b[NN + n], pz = x1b[2 * NN + n];

  float d0 = 3.4e38f, d1 = 3.4e38f, d2 = 3.4e38f;
  int i0 = 0, i1 = 0, i2 = 0;
  for (int m = 0; m < MM; ++m) {
    float dx = px - sx[m], dy = py - sy[m], dz = pz - sz[m];
    float d = dx * dx + dy * dy + dz * dz;
    if (d < d0)      { d2 = d1; i2 = i1; d1 = d0; i1 = i0; d0 = d; i0 = m; }
    else if (d < d1) { d2 = d1; i2 = i1; d1 = d;  i1 = m; }
    else if (d < d2) { d2 = d;  i2 = m; }
  }
  float a0 = 1.0f / fmaxf(d0, 1e-10f);
  float a1 = 1.0f / fmaxf(d1, 1e-10f);
  float a2 = 1.0f / fmaxf(d2, 1e-10f);
  float s = a0 + a1 + a2;
  int base = (b * NN + n) * 3;
  w_out[base + 0] = a0 / s; w_out[base + 1] = a1 / s; w_out[base + 2] = a2 / s;
  i_out[base + 0] = i0;     i_out[base + 1] = i1;     i_out[base + 2] = i2;
}

// ---------------------------------------------------------------------------
// Kernel 2: GEMM1 — h1[row, o] = sum_k feat[row,k] * W1[o,k].
// feat is built on the fly while staging the A-tile:
//   k < 256 : inverse-distance interp of points2   (gather, L2-resident)
//   k >= 256: points1[b][k-256][n]                 (coalesced over n)
// ---------------------------------------------------------------------------
__global__ __launch_bounds__(256) void gemm1_kernel(
    const float* __restrict__ p1, const float* __restrict__ p2,
    const float* __restrict__ W1, const float* __restrict__ w3,
    const int* __restrict__ i3, float* __restrict__ h1) {
  __shared__ float As[BK * LDA];
  __shared__ float Bs[BK * LDA];
  __shared__ float wsh[BM][3];
  __shared__ int   ish[BM][3];

  int t = threadIdx.x;
  int n0g = blockIdx.x * BM;       // global row base (same batch: 4096 % 64 == 0)
  int on0 = blockIdx.y * BN;
  int b = n0g >> 12;
  int n0 = n0g & 4095;

  if (t < 192) {
    int r = t / 3, j = t - 3 * r;
    wsh[r][j] = w3[(n0g + r) * 3 + j];
    ish[r][j] = i3[(n0g + r) * 3 + j];
  }
  __syncthreads();

  float acc[4][4] = {};
  int ty = t >> 4, tx = t & 15;
  const float* p2b = p2 + b * C2V * MM;
  const float* p1b = p1 + b * C1V * NN;

  for (int kt = 0; kt < KIN; kt += BK) {
    // Stage A-tile: e = j*256 + t ; m fast (coalesced points1 reads)
#pragma unroll
    for (int j = 0; j < 8; ++j) {
      int e = j * 256 + t;
      int m = e & 63, kk = e >> 6;
      int k = kt + kk;
      float v;
      if (k < C2V) {
        const float* row = p2b + k * MM;
        v = wsh[m][0] * row[ish[m][0]] + wsh[m][1] * row[ish[m][1]] +
            wsh[m][2] * row[ish[m][2]];
      } else {
        v = p1b[(k - C2V) * NN + n0 + m];
      }
      As[kk * LDA + m] = v;
    }
    // Stage B-tile from W1 (O x K row-major): kk fast -> coalesced over k
#pragma unroll
    for (int j = 0; j < 8; ++j) {
      int e = j * 256 + t;
      int kk = e & 31, oo = e >> 5;
      Bs[kk * LDA + oo] = W1[(on0 + oo) * KIN + kt + kk];
    }
    __syncthreads();
#pragma unroll
    for (int kk = 0; kk < BK; ++kk) {
      float a[4], bq[4];
#pragma unroll
      for (int i = 0; i < 4; ++i) a[i] = As[kk * LDA + ty * 4 + i];
#pragma unroll
      for (int i = 0; i < 4; ++i) bq[i] = Bs[kk * LDA + tx * 4 + i];
#pragma unroll
      for (int i = 0; i < 4; ++i)
#pragma unroll
        for (int jj = 0; jj < 4; ++jj) acc[i][jj] += a[i] * bq[jj];
    }
    __syncthreads();
  }
#pragma unroll
  for (int i = 0; i < 4; ++i) {
    int r = n0g + ty * 4 + i;
#pragma unroll
    for (int jj = 0; jj < 4; ++jj)
      h1[r * O1 + on0 + tx * 4 + jj] = acc[i][jj];
  }
}

// ---------------------------------------------------------------------------
// Kernel 3: per-channel sum / sum-of-squares over all 65536 rows.
// sums[c] and sums[256+c] must be pre-zeroed (hipMemsetAsync).
// ---------------------------------------------------------------------------
__global__ __launch_bounds__(256) void stats_kernel(
    const float* __restrict__ h, float* __restrict__ sums) {
  int c = threadIdx.x;
  int r0 = blockIdx.x * 256;
  float s = 0.0f, q = 0.0f;
  for (int r = 0; r < 256; ++r) {
    float v = h[(r0 + r) * 256 + c];
    s += v;
    q += v * v;
  }
  atomicAdd(&sums[c], s);
  atomicAdd(&sums[256 + c], q);
}

// ---------------------------------------------------------------------------
// Kernel 4: GEMM2 with BN1+ReLU fused into the A-tile load.
// ---------------------------------------------------------------------------
__global__ __launch_bounds__(256) void gemm2_kernel(
    const float* __restrict__ h1, const float* __restrict__ W2,
    const float* __restrict__ stats, const float* __restrict__ gamma1,
    const float* __restrict__ beta1, float* __restrict__ h2) {
  __shared__ float As[BK * LDA];
  __shared__ float Bs[BK * LDA];
  int t = threadIdx.x;
  int n0g = blockIdx.x * BM;
  int on0 = blockIdx.y * BN;
  float acc[4][4] = {};
  int ty = t >> 4, tx = t & 15;

  for (int kt = 0; kt < O1; kt += BK) {
    // A-tile from h1: kk fast -> coalesced over k; BN params once per thread
    {
      int kk = t & 31;
      int k = kt + kk;
      float mean = stats[k] * INV_CNT;
      float var = stats[256 + k] * INV_CNT - mean * mean;
      float sc = rsqrtf(var + EPSV) * gamma1[k];
      float bt = beta1[k] - mean * sc;
#pragma unroll
      for (int j = 0; j < 8; ++j) {
        int m = j * 8 + (t >> 5);
        float v = h1[(n0g + m) * O1 + k] * sc + bt;
        As[kk * LDA + m] = fmaxf(v, 0.0f);
      }
    }
#pragma unroll
    for (int j = 0; j < 8; ++j) {
      int e = j * 256 + t;
      int kk = e & 31, oo = e >> 5;
      Bs[kk * LDA + oo] = W2[(on0 + oo) * O1 + kt + kk];
    }
    __syncthreads();
#pragma unroll
    for (int kk = 0; kk < BK; ++kk) {
      float a[4], bq[4];
#pragma unroll
      for (int i = 0; i < 4; ++i) a[i] = As[kk * LDA + ty * 4 + i];
#pragma unroll
      for (int i = 0; i < 4; ++i) bq[i] = Bs[kk * LDA + tx * 4 + i];
#pragma unroll
      for (int i = 0; i < 4; ++i)
#pragma unroll
        for (int jj = 0; jj < 4; ++jj) acc[i][jj] += a[i] * bq[jj];
    }
    __syncthreads();
  }
#pragma unroll
  for (int i = 0; i < 4; ++i) {
    int r = n0g + ty * 4 + i;
#pragma unroll
    for (int jj = 0; jj < 4; ++jj)
      h2[r * O2 + on0 + tx * 4 + jj] = acc[i][jj];
  }
}

// ---------------------------------------------------------------------------
// Kernel 5: BN2 + ReLU + transpose (B,N,256) -> (B,256,N) via LDS tile.
// ---------------------------------------------------------------------------
__global__ __launch_bounds__(256) void bn_transpose_kernel(
    const float* __restrict__ h2, const float* __restrict__ stats2,
    const float* __restrict__ gamma2, const float* __restrict__ beta2,
    float* __restrict__ out) {
  __shared__ float tile[32][33];
  int tx = threadIdx.x & 31, ty = threadIdx.x >> 5;  // 32x8
  int n0 = blockIdx.x * 32;
  int c0 = blockIdx.y * 32;
  int b = blockIdx.z;
#pragma unroll
  for (int i = 0; i < 4; ++i) {
    int n = n0 + ty + i * 8;
    int c = c0 + tx;
    float mean = stats2[c] * INV_CNT;
    float var = stats2[256 + c] * INV_CNT - mean * mean;
    float v = (h2[((size_t)b * NN + n) * O2 + c] - mean) * rsqrtf(var + EPSV) *
                  gamma2[c] + beta2[c];
    tile[ty + i * 8][tx] = fmaxf(v, 0.0f);
  }
  __syncthreads();
#pragma unroll
  for (int i = 0; i < 4; ++i) {
    int c = c0 + ty + i * 8;
    int n = n0 + tx;
    out[((size_t)b * O2 + c) * NN + n] = tile[tx][ty + i * 8];
  }
}

// ---------------------------------------------------------------------------
// ws layout (floats): [0,196608) weights3 | [196608,393216) idx3 (int) |
// [393216,394240) stats (s1,q1,s2,q2) | [394240, +16777216) h2.
// h1 lives in d_out (exactly 65536*256 floats) and is fully overwritten by
// the final transpose kernel, which only reads h2. Total ws ~ 68.7 MB.
// ---------------------------------------------------------------------------
extern "C" void kernel_launch(void* const* d_in, const int* in_sizes, int n_in,
                              void* d_out, int out_size, void* d_ws,
                              size_t ws_size, hipStream_t stream) {
  const float* xyz1    = (const float*)d_in[0];
  const float* xyz2    = (const float*)d_in[1];
  const float* points1 = (const float*)d_in[2];
  const float* points2 = (const float*)d_in[3];
  const float* W1      = (const float*)d_in[4];
  const float* gamma1  = (const float*)d_in[5];
  const float* beta1   = (const float*)d_in[6];
  const float* W2      = (const float*)d_in[7];
  const float* gamma2  = (const float*)d_in[8];
  const float* beta2   = (const float*)d_in[9];

  float* ws    = (float*)d_ws;
  float* w3    = ws;
  int*   i3    = (int*)(ws + 196608);
  float* stats = ws + 393216;          // s1(256) q1(256) s2(256) q2(256)
  float* h2    = ws + 394240;
  float* h1    = (float*)d_out;        // reuse output buffer as h1 scratch
  float* out   = (float*)d_out;

  hipMemsetAsync(stats, 0, 1024 * sizeof(float), stream);
  knn_kernel<<<256, 256, 0, stream>>>(xyz1, xyz2, w3, i3);
  gemm1_kernel<<<dim3(1024, 4), 256, 0, stream>>>(points1, points2, W1, w3, i3, h1);
  stats_kernel<<<256, 256, 0, stream>>>(h1, stats);
  gemm2_kernel<<<dim3(1024, 4), 256, 0, stream>>>(h1, W2, stats, gamma1, beta1, h2);
  stats_kernel<<<256, 256, 0, stream>>>(h2, stats + 512);
  bn_transpose_kernel<<<dim3(128, 8, 16), 256, 0, stream>>>(h2, stats + 512,
                                                            gamma2, beta2, out);
}

// Round 2
// 408.163 us; speedup vs baseline: 2.0731x; 2.0731x over previous
//
#include <hip/hip_runtime.h>

typedef unsigned short u16;
typedef unsigned int u32;

#define BB 16
#define NN 4096
#define MM 1024
#define C1V 128
#define C2V 256
#define O1 256
#define O2 256
#define EPSV 1e-5f
#define INV_CNT (1.0f/65536.0f)

typedef __attribute__((ext_vector_type(8))) short bf16x8;
typedef __attribute__((ext_vector_type(4))) float f32x4;

static __device__ __forceinline__ u16 f2b(float f) {
  u32 u = __float_as_uint(f);
  u32 r = (u + 0x7FFFu + ((u >> 16) & 1u)) >> 16;
  return (u16)r;
}
static __device__ __forceinline__ float b2f(u16 s) {
  return __uint_as_float(((u32)s) << 16);
}

#define GLD_LDS16(gp, lp)                                                      \
  __builtin_amdgcn_global_load_lds(                                            \
      (const __attribute__((address_space(1))) void*)(gp),                     \
      (__attribute__((address_space(3))) void*)(lp), 16, 0, 0)

// ---------------------------------------------------------------------------
// Kernel 1: 3-NN search + inverse-distance weights (unchanged from round 1).
// ---------------------------------------------------------------------------
__global__ __launch_bounds__(256) void knn_kernel(
    const float* __restrict__ xyz1, const float* __restrict__ xyz2,
    float* __restrict__ w_out, int* __restrict__ i_out) {
  __shared__ float sx[MM], sy[MM], sz[MM];
  int b = blockIdx.x >> 4;
  int tile = blockIdx.x & 15;
  int t = threadIdx.x;
  const float* x2b = xyz2 + b * 3 * MM;
  for (int i = 0; i < 12; ++i) {
    int e = i * 256 + t;
    float v = x2b[e];
    int coord = e >> 10, m = e & 1023;
    float* dst = (coord == 0) ? sx : (coord == 1) ? sy : sz;
    dst[m] = v;
  }
  __syncthreads();
  int n = tile * 256 + t;
  const float* x1b = xyz1 + b * 3 * NN;
  float px = x1b[n], py = x1b[NN + n], pz = x1b[2 * NN + n];
  float d0 = 3.4e38f, d1 = 3.4e38f, d2 = 3.4e38f;
  int i0 = 0, i1 = 0, i2 = 0;
  for (int m = 0; m < MM; ++m) {
    float dx = px - sx[m], dy = py - sy[m], dz = pz - sz[m];
    float d = dx * dx + dy * dy + dz * dz;
    if (d < d0)      { d2 = d1; i2 = i1; d1 = d0; i1 = i0; d0 = d; i0 = m; }
    else if (d < d1) { d2 = d1; i2 = i1; d1 = d;  i1 = m; }
    else if (d < d2) { d2 = d;  i2 = m; }
  }
  float a0 = 1.0f / fmaxf(d0, 1e-10f);
  float a1 = 1.0f / fmaxf(d1, 1e-10f);
  float a2 = 1.0f / fmaxf(d2, 1e-10f);
  float s = a0 + a1 + a2;
  int base = (b * NN + n) * 3;
  w_out[base + 0] = a0 / s; w_out[base + 1] = a1 / s; w_out[base + 2] = a2 / s;
  i_out[base + 0] = i0;     i_out[base + 1] = i1;     i_out[base + 2] = i2;
}

// ---------------------------------------------------------------------------
// Kernel 2: fp32 -> bf16 elementwise cast (for W1, W2).
// ---------------------------------------------------------------------------
__global__ __launch_bounds__(256) void cast_w_kernel(
    const float* __restrict__ src, u16* __restrict__ dst, int n) {
  int i = blockIdx.x * 256 + threadIdx.x;
  if (i < n) dst[i] = f2b(src[i]);
}

// ---------------------------------------------------------------------------
// Kernel 3: transpose-cast (B, C, P) fp32 -> (B, P, C) bf16 via LDS tile.
// ---------------------------------------------------------------------------
__global__ __launch_bounds__(256) void tcast_kernel(
    const float* __restrict__ in, u16* __restrict__ out, int C, int P) {
  __shared__ float tile[32][33];
  int tx = threadIdx.x & 31, ty = threadIdx.x >> 5;
  int p0 = blockIdx.x * 32, c0 = blockIdx.y * 32, b = blockIdx.z;
  const float* ib = in + (size_t)b * C * P;
  u16* ob = out + (size_t)b * P * C;
#pragma unroll
  for (int i = 0; i < 4; ++i)
    tile[ty + i * 8][tx] = ib[(size_t)(c0 + ty + i * 8) * P + p0 + tx];
  __syncthreads();
#pragma unroll
  for (int i = 0; i < 4; ++i)
    ob[(size_t)(p0 + ty + i * 8) * C + c0 + tx] = f2b(tile[tx][ty + i * 8]);
}

// ---------------------------------------------------------------------------
// MFMA GEMM: out[row, o] = sum_k A[row,k]*B[o,k], A (MxK bf16, lda), B (o-major
// bf16, ldb), out cols = 256 (o0 tiles of 128). 128x128 block tile, 4 waves in
// 2x2, each wave 64x64 via 4x4 mfma_f32_16x16x32_bf16.
//   INTERP: acc += sum_j w3[row][j] * G[b*1024 + i3[row][j]][col]
//   STATS : per-column sum / sumsq atomics into stats[0:256]/stats[256:512]
//   OUTB  : store bf16 (else fp32)
// ---------------------------------------------------------------------------
template <int K, bool INTERP, bool STATS, bool OUTB>
__global__ __launch_bounds__(256) void gemm_mfma(
    const u16* __restrict__ A, int lda, const u16* __restrict__ B, int ldb,
    void* __restrict__ out, const float* __restrict__ G,
    const float* __restrict__ w3, const int* __restrict__ i3,
    float* __restrict__ stats) {
  __shared__ u16 As[128 * 32];
  __shared__ u16 Bs[128 * 32];
  __shared__ float wsh[128][3];
  __shared__ int ish[128][3];

  int t = threadIdx.x;
  int w = t >> 6, l = t & 63;
  int n0 = blockIdx.x * 128;  // row base
  int o0 = blockIdx.y * 128;  // col base

  if (INTERP) {
    for (int e = t; e < 384; e += 256) {
      int r = e / 3, j = e - 3 * r;
      wsh[r][j] = w3[(n0 + r) * 3 + j];
      ish[r][j] = i3[(n0 + r) * 3 + j];
    }
  }

  int wm = w & 1, wn = w >> 1;
  int lr = l >> 2, lc = l & 3;     // staging: row-in-16, 16B chunk
  int q = l >> 4, m = l & 15;      // mfma lane decomposition

  f32x4 acc[4][4] = {};

  const u16* arow = A + (size_t)n0 * lda;
  const u16* brow = B + (size_t)o0 * ldb;

#pragma unroll
  for (int kt = 0; kt < K; kt += 32) {
    __syncthreads();
#pragma unroll
    for (int r = 0; r < 2; ++r) {
      int row = r * 64 + w * 16 + lr;
      GLD_LDS16(arow + (size_t)row * lda + kt + lc * 8, As + row * 32 + lc * 8);
    }
#pragma unroll
    for (int r = 0; r < 2; ++r) {
      int row = r * 64 + w * 16 + lr;
      GLD_LDS16(brow + (size_t)row * ldb + kt + lc * 8, Bs + row * 32 + lc * 8);
    }
    __syncthreads();
    bf16x8 af[4], bf[4];
#pragma unroll
    for (int i = 0; i < 4; ++i)
      af[i] = *(const bf16x8*)(As + (wm * 64 + i * 16 + m) * 32 + q * 8);
#pragma unroll
    for (int j = 0; j < 4; ++j)
      bf[j] = *(const bf16x8*)(Bs + (wn * 64 + j * 16 + m) * 32 + q * 8);
#pragma unroll
    for (int i = 0; i < 4; ++i)
#pragma unroll
      for (int j = 0; j < 4; ++j)
        acc[i][j] =
            __builtin_amdgcn_mfma_f32_16x16x32_bf16(af[i], bf[j], acc[i][j], 0, 0, 0);
  }

  // --- epilogue ---
  if (INTERP) {
    int b = n0 >> 12;
#pragma unroll
    for (int i = 0; i < 4; ++i) {
#pragma unroll
      for (int reg = 0; reg < 4; ++reg) {
        int rl = wm * 64 + i * 16 + q * 4 + reg;
        float w0 = wsh[rl][0], w1 = wsh[rl][1], w2 = wsh[rl][2];
        const float* g0 = G + ((size_t)(b * 1024 + ish[rl][0])) * 256 + o0;
        const float* g1 = G + ((size_t)(b * 1024 + ish[rl][1])) * 256 + o0;
        const float* g2 = G + ((size_t)(b * 1024 + ish[rl][2])) * 256 + o0;
#pragma unroll
        for (int j = 0; j < 4; ++j) {
          int c = wn * 64 + j * 16 + m;
          acc[i][j][reg] += w0 * g0[c] + w1 * g1[c] + w2 * g2[c];
        }
      }
    }
  }

  if (STATS) {
#pragma unroll
    for (int j = 0; j < 4; ++j) {
      float s = 0.0f, ss = 0.0f;
#pragma unroll
      for (int i = 0; i < 4; ++i)
#pragma unroll
        for (int reg = 0; reg < 4; ++reg) {
          float v = acc[i][j][reg];
          s += v;
          ss += v * v;
        }
      s += __shfl_down(s, 32); ss += __shfl_down(ss, 32);
      s += __shfl_down(s, 16); ss += __shfl_down(ss, 16);
      if (l < 16) {
        int c = o0 + wn * 64 + j * 16 + l;
        atomicAdd(&stats[c], s);
        atomicAdd(&stats[256 + c], ss);
      }
    }
  }

#pragma unroll
  for (int i = 0; i < 4; ++i) {
    int gr = n0 + wm * 64 + i * 16 + q * 4;
#pragma unroll
    for (int reg = 0; reg < 4; ++reg) {
#pragma unroll
      for (int j = 0; j < 4; ++j) {
        int gc = o0 + wn * 64 + j * 16 + m;
        size_t off = (size_t)(gr + reg) * 256 + gc;
        if (OUTB)
          ((u16*)out)[off] = f2b(acc[i][j][reg]);
        else
          ((float*)out)[off] = acc[i][j][reg];
      }
    }
  }
}

// ---------------------------------------------------------------------------
// Kernel 5: BN1 + ReLU + cast h1(bf16) -> a2(bf16). 16B per thread per pass.
// ---------------------------------------------------------------------------
__global__ __launch_bounds__(256) void bnrelu_kernel(
    const u16* __restrict__ h1, const float* __restrict__ stats,
    const float* __restrict__ gamma, const float* __restrict__ beta,
    u16* __restrict__ a2) {
  __shared__ float sc[256], sh[256];
  int t = threadIdx.x;
  {
    float mean = stats[t] * INV_CNT;
    float var = stats[256 + t] * INV_CNT - mean * mean;
    float s = rsqrtf(var + EPSV) * gamma[t];
    sc[t] = s;
    sh[t] = beta[t] - mean * s;
  }
  __syncthreads();
  size_t base = ((size_t)blockIdx.x * 256 + t) * 8;
  int c0 = (t & 31) * 8;
  union { uint4 u; u16 s[8]; } in_, out_;
  in_.u = *(const uint4*)(h1 + base);
#pragma unroll
  for (int j = 0; j < 8; ++j) {
    float f = b2f(in_.s[j]) * sc[c0 + j] + sh[c0 + j];
    out_.s[j] = f2b(fmaxf(f, 0.0f));
  }
  *(uint4*)(a2 + base) = out_.u;
}

// ---------------------------------------------------------------------------
// Kernel 6: BN2 + ReLU + transpose h2(bf16, B*N x 256) -> out fp32 (B,256,N).
// ---------------------------------------------------------------------------
__global__ __launch_bounds__(256) void bn2t_kernel(
    const u16* __restrict__ h2, const float* __restrict__ stats,
    const float* __restrict__ gamma, const float* __restrict__ beta,
    float* __restrict__ out) {
  __shared__ float tile[32][33];
  int tx = threadIdx.x & 31, ty = threadIdx.x >> 5;
  int n0 = blockIdx.x * 32, c0 = blockIdx.y * 32, b = blockIdx.z;
  int c = c0 + tx;
  float mean = stats[c] * INV_CNT;
  float var = stats[256 + c] * INV_CNT - mean * mean;
  float s = rsqrtf(var + EPSV) * gamma[c];
  float sh = beta[c] - mean * s;
#pragma unroll
  for (int i = 0; i < 4; ++i) {
    int n = n0 + ty + i * 8;
    float v = b2f(h2[((size_t)b * NN + n) * 256 + c]) * s + sh;
    tile[ty + i * 8][tx] = fmaxf(v, 0.0f);
  }
  __syncthreads();
#pragma unroll
  for (int i = 0; i < 4; ++i)
    out[((size_t)b * 256 + c0 + ty + i * 8) * NN + n0 + tx] = tile[tx][ty + i * 8];
}

// ---------------------------------------------------------------------------
// ws layout (bytes):
//   0        w3       786432
//   786432   i3       786432
//   1572864  stats    4096    (s1,q1,s2,q2)
//   1576960  W1b      196608
//   1773568  W2b      131072
//   1904640  p2t      8388608   \
//   10293248 p1t      16777216   } a2 (33.5MB) aliases this 41.9MB region
//   27070464 G        16777216  /
//   43847680 h2b      33554432
//   total ~77.4 MB.  h1b (bf16) lives in d_out (67MB), overwritten at the end.
// ---------------------------------------------------------------------------
extern "C" void kernel_launch(void* const* d_in, const int* in_sizes, int n_in,
                              void* d_out, int out_size, void* d_ws,
                              size_t ws_size, hipStream_t stream) {
  const float* xyz1    = (const float*)d_in[0];
  const float* xyz2    = (const float*)d_in[1];
  const float* points1 = (const float*)d_in[2];
  const float* points2 = (const float*)d_in[3];
  const float* W1      = (const float*)d_in[4];
  const float* gamma1  = (const float*)d_in[5];
  const float* beta1   = (const float*)d_in[6];
  const float* W2      = (const float*)d_in[7];
  const float* gamma2  = (const float*)d_in[8];
  const float* beta2   = (const float*)d_in[9];

  char* ws = (char*)d_ws;
  float* w3    = (float*)(ws + 0);
  int*   i3    = (int*)(ws + 786432);
  float* stats = (float*)(ws + 1572864);
  u16*   W1b   = (u16*)(ws + 1576960);
  u16*   W2b   = (u16*)(ws + 1773568);
  u16*   p2t   = (u16*)(ws + 1904640);
  u16*   p1t   = (u16*)(ws + 10293248);
  float* G     = (float*)(ws + 27070464);
  u16*   a2    = (u16*)(ws + 1904640);   // alias p2t/p1t/G (dead by then)
  u16*   h2b   = (u16*)(ws + 43847680);
  u16*   h1b   = (u16*)d_out;            // h1 bf16 scratch inside output buf
  float* out   = (float*)d_out;

  hipMemsetAsync(stats, 0, 4096, stream);
  knn_kernel<<<256, 256, 0, stream>>>(xyz1, xyz2, w3, i3);
  cast_w_kernel<<<384, 256, 0, stream>>>(W1, W1b, 98304);
  cast_w_kernel<<<256, 256, 0, stream>>>(W2, W2b, 65536);
  tcast_kernel<<<dim3(32, 8, 16), 256, 0, stream>>>(points2, p2t, C2V, MM);
  tcast_kernel<<<dim3(128, 4, 16), 256, 0, stream>>>(points1, p1t, C1V, NN);
  // G = p2^T * W1[:, 0:256]^T : (16*1024) x 256, K=256, fp32 out
  gemm_mfma<256, false, false, false><<<dim3(128, 2), 256, 0, stream>>>(
      p2t, 256, W1b, 384, G, nullptr, nullptr, nullptr, nullptr);
  // h1 = p1t * W1[:, 256:384]^T + interp(G);  stats1 atomics; bf16 out
  gemm_mfma<128, true, true, true><<<dim3(512, 2), 256, 0, stream>>>(
      p1t, 128, W1b + 256, 384, h1b, G, w3, i3, stats);
  bnrelu_kernel<<<8192, 256, 0, stream>>>(h1b, stats, gamma1, beta1, a2);
  // h2 = a2 * W2^T; stats2 atomics; bf16 out
  gemm_mfma<256, false, true, true><<<dim3(512, 2), 256, 0, stream>>>(
      a2, 256, W2b, 256, h2b, nullptr, nullptr, nullptr, stats + 512);
  bn2t_kernel<<<dim3(128, 8, 16), 256, 0, stream>>>(h2b, stats + 512, gamma2,
                                                    beta2, out);
}

// Round 3
// 307.810 us; speedup vs baseline: 2.7490x; 1.3260x over previous
//
#include <hip/hip_runtime.h>

typedef unsigned short u16;
typedef unsigned int u32;

#define BB 16
#define NN 4096
#define MM 1024
#define C1V 128
#define C2V 256
#define O1 256
#define O2 256
#define EPSV 1e-5f
#define INV_CNT (1.0f/65536.0f)

typedef __attribute__((ext_vector_type(8))) short bf16x8;
typedef __attribute__((ext_vector_type(4))) float f32x4;

static __device__ __forceinline__ u16 f2b(float f) {
  u32 u = __float_as_uint(f);
  u32 r = (u + 0x7FFFu + ((u >> 16) & 1u)) >> 16;
  return (u16)r;
}
static __device__ __forceinline__ float b2f(u16 s) {
  return __uint_as_float(((u32)s) << 16);
}

#define GLD_LDS16(gp, lp)                                                      \
  __builtin_amdgcn_global_load_lds(                                            \
      (const __attribute__((address_space(1))) void*)(gp),                     \
      (__attribute__((address_space(3))) void*)(lp), 16, 0, 0)

// ---------------------------------------------------------------------------
// Kernel 1: 3-NN partials. Grid 512 = b(16) x qtile(8) x chunk(4).
// Each block: 256 candidates staged as float4(x,y,z,norm) in LDS; 256 threads
// x 2 queries each (ILP-2). Comparison key = |c|^2 - 2 p.c (order-preserving,
// query-norm added back at writeout). Top-3 kept branchless per query.
// ---------------------------------------------------------------------------
__global__ __launch_bounds__(256) void knn_kernel(
    const float* __restrict__ xyz1, const float* __restrict__ xyz2,
    float* __restrict__ pd, int* __restrict__ pi) {
  __shared__ float4 cand[256];
  int bx = blockIdx.x;
  int c = bx & 3;
  int qt = (bx >> 2) & 7;
  int b = bx >> 5;
  int t = threadIdx.x;

  const float* x2b = xyz2 + b * 3 * MM;
  {
    float x = x2b[c * 256 + t];
    float y = x2b[MM + c * 256 + t];
    float z = x2b[2 * MM + c * 256 + t];
    cand[t] = make_float4(x, y, z, x * x + y * y + z * z);
  }
  __syncthreads();

  const float* x1b = xyz1 + b * 3 * NN;
  int n0 = qt * 512 + t;
  int n1 = n0 + 256;
  float px0 = x1b[n0], py0 = x1b[NN + n0], pz0 = x1b[2 * NN + n0];
  float px1 = x1b[n1], py1 = x1b[NN + n1], pz1 = x1b[2 * NN + n1];

  const float INF = 3.4e38f;
  float k00 = INF, k01 = INF, k02 = INF;
  float k10 = INF, k11 = INF, k12 = INF;
  int j00 = 0, j01 = 0, j02 = 0;
  int j10 = 0, j11 = 0, j12 = 0;

#pragma unroll 8
  for (int m = 0; m < 256; ++m) {
    float4 cd = cand[m];
    {
      float dot = fmaf(px0, cd.x, fmaf(py0, cd.y, pz0 * cd.z));
      float key = fmaf(-2.0f, dot, cd.w);
      bool c0 = key < k00, c1 = key < k01, c2 = key < k02;
      k02 = c1 ? k01 : (c2 ? key : k02);
      j02 = c1 ? j01 : (c2 ? m : j02);
      k01 = c0 ? k00 : (c1 ? key : k01);
      j01 = c0 ? j00 : (c1 ? m : j01);
      k00 = c0 ? key : k00;
      j00 = c0 ? m : j00;
    }
    {
      float dot = fmaf(px1, cd.x, fmaf(py1, cd.y, pz1 * cd.z));
      float key = fmaf(-2.0f, dot, cd.w);
      bool c0 = key < k10, c1 = key < k11, c2 = key < k12;
      k12 = c1 ? k11 : (c2 ? key : k12);
      j12 = c1 ? j11 : (c2 ? m : j12);
      k11 = c0 ? k10 : (c1 ? key : k11);
      j11 = c0 ? j10 : (c1 ? m : j11);
      k10 = c0 ? key : k10;
      j10 = c0 ? m : j10;
    }
  }

  float pn0 = px0 * px0 + py0 * py0 + pz0 * pz0;
  float pn1 = px1 * px1 + py1 * py1 + pz1 * pz1;
  int gq0 = b * NN + n0;
  int gq1 = b * NN + n1;
  int base = c << 8;
  ((float4*)pd)[(size_t)c * 65536 + gq0] =
      make_float4(fmaxf(k00 + pn0, 1e-10f), fmaxf(k01 + pn0, 1e-10f),
                  fmaxf(k02 + pn0, 1e-10f), 0.0f);
  ((int4*)pi)[(size_t)c * 65536 + gq0] =
      make_int4(base + j00, base + j01, base + j02, 0);
  ((float4*)pd)[(size_t)c * 65536 + gq1] =
      make_float4(fmaxf(k10 + pn1, 1e-10f), fmaxf(k11 + pn1, 1e-10f),
                  fmaxf(k12 + pn1, 1e-10f), 0.0f);
  ((int4*)pi)[(size_t)c * 65536 + gq1] =
      make_int4(base + j10, base + j11, base + j12, 0);
}

// ---------------------------------------------------------------------------
// Kernel 1b: merge 4 chunk top-3s -> final top-3, inverse-distance weights.
// ---------------------------------------------------------------------------
__global__ __launch_bounds__(256) void knn_merge(
    const float* __restrict__ pd, const int* __restrict__ pi,
    float* __restrict__ w_out, int* __restrict__ i_out) {
  int gq = blockIdx.x * 256 + threadIdx.x;
  float4 d0 = ((const float4*)pd)[gq];
  int4 i0 = ((const int4*)pi)[gq];
  float a0 = d0.x, a1 = d0.y, a2 = d0.z;
  int b0 = i0.x, b1 = i0.y, b2 = i0.z;
#pragma unroll
  for (int c = 1; c < 4; ++c) {
    float4 dc = ((const float4*)pd)[(size_t)c * 65536 + gq];
    int4 ic = ((const int4*)pi)[(size_t)c * 65536 + gq];
    float kv[3] = {dc.x, dc.y, dc.z};
    int jv[3] = {ic.x, ic.y, ic.z};
#pragma unroll
    for (int j = 0; j < 3; ++j) {
      float key = kv[j];
      int idx = jv[j];
      bool c0 = key < a0, c1 = key < a1, c2 = key < a2;
      a2 = c1 ? a1 : (c2 ? key : a2);
      b2 = c1 ? b1 : (c2 ? idx : b2);
      a1 = c0 ? a0 : (c1 ? key : a1);
      b1 = c0 ? b0 : (c1 ? idx : b1);
      a0 = c0 ? key : a0;
      b0 = c0 ? idx : b0;
    }
  }
  float v0 = 1.0f / a0, v1 = 1.0f / a1, v2 = 1.0f / a2;
  float s = 1.0f / (v0 + v1 + v2);
  int base = gq * 3;
  w_out[base + 0] = v0 * s;
  w_out[base + 1] = v1 * s;
  w_out[base + 2] = v2 * s;
  i_out[base + 0] = b0;
  i_out[base + 1] = b1;
  i_out[base + 2] = b2;
}

// ---------------------------------------------------------------------------
// Kernel 2: fp32 -> bf16 elementwise cast (for W1, W2).
// ---------------------------------------------------------------------------
__global__ __launch_bounds__(256) void cast_w_kernel(
    const float* __restrict__ src, u16* __restrict__ dst, int n) {
  int i = blockIdx.x * 256 + threadIdx.x;
  if (i < n) dst[i] = f2b(src[i]);
}

// ---------------------------------------------------------------------------
// Kernel 3: transpose-cast (B, C, P) fp32 -> (B, P, C) bf16 via LDS tile.
// ---------------------------------------------------------------------------
__global__ __launch_bounds__(256) void tcast_kernel(
    const float* __restrict__ in, u16* __restrict__ out, int C, int P) {
  __shared__ float tile[32][33];
  int tx = threadIdx.x & 31, ty = threadIdx.x >> 5;
  int p0 = blockIdx.x * 32, c0 = blockIdx.y * 32, b = blockIdx.z;
  const float* ib = in + (size_t)b * C * P;
  u16* ob = out + (size_t)b * P * C;
#pragma unroll
  for (int i = 0; i < 4; ++i)
    tile[ty + i * 8][tx] = ib[(size_t)(c0 + ty + i * 8) * P + p0 + tx];
  __syncthreads();
#pragma unroll
  for (int i = 0; i < 4; ++i)
    ob[(size_t)(p0 + ty + i * 8) * C + c0 + tx] = f2b(tile[tx][ty + i * 8]);
}

// ---------------------------------------------------------------------------
// MFMA GEMM (unchanged from round 2): 128x128 tile, 4 waves 2x2, 4x4
// mfma_f32_16x16x32_bf16 each. INTERP adds the 3-NN gather of G in the
// epilogue; STATS does per-column sum/sumsq atomics; OUTB stores bf16.
// ---------------------------------------------------------------------------
template <int K, bool INTERP, bool STATS, bool OUTB>
__global__ __launch_bounds__(256) void gemm_mfma(
    const u16* __restrict__ A, int lda, const u16* __restrict__ B, int ldb,
    void* __restrict__ out, const float* __restrict__ G,
    const float* __restrict__ w3, const int* __restrict__ i3,
    float* __restrict__ stats) {
  __shared__ u16 As[128 * 32];
  __shared__ u16 Bs[128 * 32];
  __shared__ float wsh[128][3];
  __shared__ int ish[128][3];

  int t = threadIdx.x;
  int w = t >> 6, l = t & 63;
  int n0 = blockIdx.x * 128;
  int o0 = blockIdx.y * 128;

  if (INTERP) {
    for (int e = t; e < 384; e += 256) {
      int r = e / 3, j = e - 3 * r;
      wsh[r][j] = w3[(n0 + r) * 3 + j];
      ish[r][j] = i3[(n0 + r) * 3 + j];
    }
  }

  int wm = w & 1, wn = w >> 1;
  int lr = l >> 2, lc = l & 3;
  int q = l >> 4, m = l & 15;

  f32x4 acc[4][4] = {};

  const u16* arow = A + (size_t)n0 * lda;
  const u16* brow = B + (size_t)o0 * ldb;

#pragma unroll
  for (int kt = 0; kt < K; kt += 32) {
    __syncthreads();
#pragma unroll
    for (int r = 0; r < 2; ++r) {
      int row = r * 64 + w * 16 + lr;
      GLD_LDS16(arow + (size_t)row * lda + kt + lc * 8, As + row * 32 + lc * 8);
    }
#pragma unroll
    for (int r = 0; r < 2; ++r) {
      int row = r * 64 + w * 16 + lr;
      GLD_LDS16(brow + (size_t)row * ldb + kt + lc * 8, Bs + row * 32 + lc * 8);
    }
    __syncthreads();
    bf16x8 af[4], bf[4];
#pragma unroll
    for (int i = 0; i < 4; ++i)
      af[i] = *(const bf16x8*)(As + (wm * 64 + i * 16 + m) * 32 + q * 8);
#pragma unroll
    for (int j = 0; j < 4; ++j)
      bf[j] = *(const bf16x8*)(Bs + (wn * 64 + j * 16 + m) * 32 + q * 8);
#pragma unroll
    for (int i = 0; i < 4; ++i)
#pragma unroll
      for (int j = 0; j < 4; ++j)
        acc[i][j] =
            __builtin_amdgcn_mfma_f32_16x16x32_bf16(af[i], bf[j], acc[i][j], 0, 0, 0);
  }

  if (INTERP) {
    int b = n0 >> 12;
#pragma unroll
    for (int i = 0; i < 4; ++i) {
#pragma unroll
      for (int reg = 0; reg < 4; ++reg) {
        int rl = wm * 64 + i * 16 + q * 4 + reg;
        float w0 = wsh[rl][0], w1 = wsh[rl][1], w2 = wsh[rl][2];
        const float* g0 = G + ((size_t)(b * 1024 + ish[rl][0])) * 256 + o0;
        const float* g1 = G + ((size_t)(b * 1024 + ish[rl][1])) * 256 + o0;
        const float* g2 = G + ((size_t)(b * 1024 + ish[rl][2])) * 256 + o0;
#pragma unroll
        for (int j = 0; j < 4; ++j) {
          int c = wn * 64 + j * 16 + m;
          acc[i][j][reg] += w0 * g0[c] + w1 * g1[c] + w2 * g2[c];
        }
      }
    }
  }

  if (STATS) {
#pragma unroll
    for (int j = 0; j < 4; ++j) {
      float s = 0.0f, ss = 0.0f;
#pragma unroll
      for (int i = 0; i < 4; ++i)
#pragma unroll
        for (int reg = 0; reg < 4; ++reg) {
          float v = acc[i][j][reg];
          s += v;
          ss += v * v;
        }
      s += __shfl_down(s, 32); ss += __shfl_down(ss, 32);
      s += __shfl_down(s, 16); ss += __shfl_down(ss, 16);
      if (l < 16) {
        int c = o0 + wn * 64 + j * 16 + l;
        atomicAdd(&stats[c], s);
        atomicAdd(&stats[256 + c], ss);
      }
    }
  }

#pragma unroll
  for (int i = 0; i < 4; ++i) {
    int gr = n0 + wm * 64 + i * 16 + q * 4;
#pragma unroll
    for (int reg = 0; reg < 4; ++reg) {
#pragma unroll
      for (int j = 0; j < 4; ++j) {
        int gc = o0 + wn * 64 + j * 16 + m;
        size_t off = (size_t)(gr + reg) * 256 + gc;
        if (OUTB)
          ((u16*)out)[off] = f2b(acc[i][j][reg]);
        else
          ((float*)out)[off] = acc[i][j][reg];
      }
    }
  }
}

// ---------------------------------------------------------------------------
// Kernel 5: BN1 + ReLU + cast h1(bf16) -> a2(bf16).
// ---------------------------------------------------------------------------
__global__ __launch_bounds__(256) void bnrelu_kernel(
    const u16* __restrict__ h1, const float* __restrict__ stats,
    const float* __restrict__ gamma, const float* __restrict__ beta,
    u16* __restrict__ a2) {
  __shared__ float sc[256], sh[256];
  int t = threadIdx.x;
  {
    float mean = stats[t] * INV_CNT;
    float var = stats[256 + t] * INV_CNT - mean * mean;
    float s = rsqrtf(var + EPSV) * gamma[t];
    sc[t] = s;
    sh[t] = beta[t] - mean * s;
  }
  __syncthreads();
  size_t base = ((size_t)blockIdx.x * 256 + t) * 8;
  int c0 = (t & 31) * 8;
  union { uint4 u; u16 s[8]; } in_, out_;
  in_.u = *(const uint4*)(h1 + base);
#pragma unroll
  for (int j = 0; j < 8; ++j) {
    float f = b2f(in_.s[j]) * sc[c0 + j] + sh[c0 + j];
    out_.s[j] = f2b(fmaxf(f, 0.0f));
  }
  *(uint4*)(a2 + base) = out_.u;
}

// ---------------------------------------------------------------------------
// Kernel 6: BN2 + ReLU + transpose h2(bf16, B*N x 256) -> out fp32 (B,256,N).
// ---------------------------------------------------------------------------
__global__ __launch_bounds__(256) void bn2t_kernel(
    const u16* __restrict__ h2, const float* __restrict__ stats,
    const float* __restrict__ gamma, const float* __restrict__ beta,
    float* __restrict__ out) {
  __shared__ float tile[32][33];
  int tx = threadIdx.x & 31, ty = threadIdx.x >> 5;
  int n0 = blockIdx.x * 32, c0 = blockIdx.y * 32, b = blockIdx.z;
  int c = c0 + tx;
  float mean = stats[c] * INV_CNT;
  float var = stats[256 + c] * INV_CNT - mean * mean;
  float s = rsqrtf(var + EPSV) * gamma[c];
  float sh = beta[c] - mean * s;
#pragma unroll
  for (int i = 0; i < 4; ++i) {
    int n = n0 + ty + i * 8;
    float v = b2f(h2[((size_t)b * NN + n) * 256 + c]) * s + sh;
    tile[ty + i * 8][tx] = fmaxf(v, 0.0f);
  }
  __syncthreads();
#pragma unroll
  for (int i = 0; i < 4; ++i)
    out[((size_t)b * 256 + c0 + ty + i * 8) * NN + n0 + tx] = tile[tx][ty + i * 8];
}

// ---------------------------------------------------------------------------
// ws layout (bytes):
//   0        w3       786432
//   786432   i3       786432
//   1572864  stats    4096
//   1576960  W1b      196608
//   1773568  W2b      131072
//   1904640  p2t      8388608   \  pd (4.2MB) + pi (4.2MB) alias this region
//   10293248 p1t      16777216   } during knn/merge (dead before tcast);
//   27070464 G        16777216  /  a2 (33.5MB) aliases it after bnrelu
//   43847680 h2b      33554432
// h1b (bf16) lives in d_out, overwritten by the final transpose.
// ---------------------------------------------------------------------------
extern "C" void kernel_launch(void* const* d_in, const int* in_sizes, int n_in,
                              void* d_out, int out_size, void* d_ws,
                              size_t ws_size, hipStream_t stream) {
  const float* xyz1    = (const float*)d_in[0];
  const float* xyz2    = (const float*)d_in[1];
  const float* points1 = (const float*)d_in[2];
  const float* points2 = (const float*)d_in[3];
  const float* W1      = (const float*)d_in[4];
  const float* gamma1  = (const float*)d_in[5];
  const float* beta1   = (const float*)d_in[6];
  const float* W2      = (const float*)d_in[7];
  const float* gamma2  = (const float*)d_in[8];
  const float* beta2   = (const float*)d_in[9];

  char* ws = (char*)d_ws;
  float* w3    = (float*)(ws + 0);
  int*   i3    = (int*)(ws + 786432);
  float* stats = (float*)(ws + 1572864);
  u16*   W1b   = (u16*)(ws + 1576960);
  u16*   W2b   = (u16*)(ws + 1773568);
  float* pd    = (float*)(ws + 1904640);             // knn partial dists
  int*   pi    = (int*)(ws + 1904640 + 4194304);     // knn partial indices
  u16*   p2t   = (u16*)(ws + 1904640);
  u16*   p1t   = (u16*)(ws + 10293248);
  float* G     = (float*)(ws + 27070464);
  u16*   a2    = (u16*)(ws + 1904640);
  u16*   h2b   = (u16*)(ws + 43847680);
  u16*   h1b   = (u16*)d_out;
  float* out   = (float*)d_out;

  hipMemsetAsync(stats, 0, 4096, stream);
  knn_kernel<<<512, 256, 0, stream>>>(xyz1, xyz2, pd, pi);
  knn_merge<<<256, 256, 0, stream>>>(pd, pi, w3, i3);
  cast_w_kernel<<<384, 256, 0, stream>>>(W1, W1b, 98304);
  cast_w_kernel<<<256, 256, 0, stream>>>(W2, W2b, 65536);
  tcast_kernel<<<dim3(32, 8, 16), 256, 0, stream>>>(points2, p2t, C2V, MM);
  tcast_kernel<<<dim3(128, 4, 16), 256, 0, stream>>>(points1, p1t, C1V, NN);
  gemm_mfma<256, false, false, false><<<dim3(128, 2), 256, 0, stream>>>(
      p2t, 256, W1b, 384, G, nullptr, nullptr, nullptr, nullptr);
  gemm_mfma<128, true, true, true><<<dim3(512, 2), 256, 0, stream>>>(
      p1t, 128, W1b + 256, 384, h1b, G, w3, i3, stats);
  bnrelu_kernel<<<8192, 256, 0, stream>>>(h1b, stats, gamma1, beta1, a2);
  gemm_mfma<256, false, true, true><<<dim3(512, 2), 256, 0, stream>>>(
      a2, 256, W2b, 256, h2b, nullptr, nullptr, nullptr, stats + 512);
  bn2t_kernel<<<dim3(128, 8, 16), 256, 0, stream>>>(h2b, stats + 512, gamma2,
                                                    beta2, out);
}

// Round 4
// 305.366 us; speedup vs baseline: 2.7710x; 1.0080x over previous
//
#include <hip/hip_runtime.h>

typedef unsigned short u16;
typedef unsigned int u32;

#define BB 16
#define NN 4096
#define MM 1024
#define C1V 128
#define C2V 256
#define O1 256
#define O2 256
#define EPSV 1e-5f
#define INV_CNT (1.0f/65536.0f)

typedef __attribute__((ext_vector_type(8))) short bf16x8;
typedef __attribute__((ext_vector_type(4))) float f32x4;

static __device__ __forceinline__ u16 f2b(float f) {
  u32 u = __float_as_uint(f);
  u32 r = (u + 0x7FFFu + ((u >> 16) & 1u)) >> 16;
  return (u16)r;
}
static __device__ __forceinline__ float b2f(u16 s) {
  return __uint_as_float(((u32)s) << 16);
}

#define GLD_LDS16(gp, lp)                                                      \
  __builtin_amdgcn_global_load_lds(                                            \
      (const __attribute__((address_space(1))) void*)(gp),                     \
      (__attribute__((address_space(3))) void*)(lp), 16, 0, 0)

// ---------------------------------------------------------------------------
// Kernel 1: 3-NN partials. Grid 512 = b(16) x qtile(8) x chunk(4).
// ---------------------------------------------------------------------------
__global__ __launch_bounds__(256) void knn_kernel(
    const float* __restrict__ xyz1, const float* __restrict__ xyz2,
    float* __restrict__ pd, int* __restrict__ pi) {
  __shared__ float4 cand[256];
  int bx = blockIdx.x;
  int c = bx & 3;
  int qt = (bx >> 2) & 7;
  int b = bx >> 5;
  int t = threadIdx.x;

  const float* x2b = xyz2 + b * 3 * MM;
  {
    float x = x2b[c * 256 + t];
    float y = x2b[MM + c * 256 + t];
    float z = x2b[2 * MM + c * 256 + t];
    cand[t] = make_float4(x, y, z, x * x + y * y + z * z);
  }
  __syncthreads();

  const float* x1b = xyz1 + b * 3 * NN;
  int n0 = qt * 512 + t;
  int n1 = n0 + 256;
  float px0 = x1b[n0], py0 = x1b[NN + n0], pz0 = x1b[2 * NN + n0];
  float px1 = x1b[n1], py1 = x1b[NN + n1], pz1 = x1b[2 * NN + n1];

  const float INF = 3.4e38f;
  float k00 = INF, k01 = INF, k02 = INF;
  float k10 = INF, k11 = INF, k12 = INF;
  int j00 = 0, j01 = 0, j02 = 0;
  int j10 = 0, j11 = 0, j12 = 0;

#pragma unroll 8
  for (int m = 0; m < 256; ++m) {
    float4 cd = cand[m];
    {
      float dot = fmaf(px0, cd.x, fmaf(py0, cd.y, pz0 * cd.z));
      float key = fmaf(-2.0f, dot, cd.w);
      bool c0 = key < k00, c1 = key < k01, c2 = key < k02;
      k02 = c1 ? k01 : (c2 ? key : k02);
      j02 = c1 ? j01 : (c2 ? m : j02);
      k01 = c0 ? k00 : (c1 ? key : k01);
      j01 = c0 ? j00 : (c1 ? m : j01);
      k00 = c0 ? key : k00;
      j00 = c0 ? m : j00;
    }
    {
      float dot = fmaf(px1, cd.x, fmaf(py1, cd.y, pz1 * cd.z));
      float key = fmaf(-2.0f, dot, cd.w);
      bool c0 = key < k10, c1 = key < k11, c2 = key < k12;
      k12 = c1 ? k11 : (c2 ? key : k12);
      j12 = c1 ? j11 : (c2 ? m : j12);
      k11 = c0 ? k10 : (c1 ? key : k11);
      j11 = c0 ? j10 : (c1 ? m : j11);
      k10 = c0 ? key : k10;
      j10 = c0 ? m : j10;
    }
  }

  float pn0 = px0 * px0 + py0 * py0 + pz0 * pz0;
  float pn1 = px1 * px1 + py1 * py1 + pz1 * pz1;
  int gq0 = b * NN + n0;
  int gq1 = b * NN + n1;
  int base = c << 8;
  ((float4*)pd)[(size_t)c * 65536 + gq0] =
      make_float4(fmaxf(k00 + pn0, 1e-10f), fmaxf(k01 + pn0, 1e-10f),
                  fmaxf(k02 + pn0, 1e-10f), 0.0f);
  ((int4*)pi)[(size_t)c * 65536 + gq0] =
      make_int4(base + j00, base + j01, base + j02, 0);
  ((float4*)pd)[(size_t)c * 65536 + gq1] =
      make_float4(fmaxf(k10 + pn1, 1e-10f), fmaxf(k11 + pn1, 1e-10f),
                  fmaxf(k12 + pn1, 1e-10f), 0.0f);
  ((int4*)pi)[(size_t)c * 65536 + gq1] =
      make_int4(base + j10, base + j11, base + j12, 0);
}

// ---------------------------------------------------------------------------
// Kernel 1b: merge 4 chunk top-3s -> final top-3, inverse-distance weights.
// ---------------------------------------------------------------------------
__global__ __launch_bounds__(256) void knn_merge(
    const float* __restrict__ pd, const int* __restrict__ pi,
    float* __restrict__ w_out, int* __restrict__ i_out) {
  int gq = blockIdx.x * 256 + threadIdx.x;
  float4 d0 = ((const float4*)pd)[gq];
  int4 i0 = ((const int4*)pi)[gq];
  float a0 = d0.x, a1 = d0.y, a2 = d0.z;
  int b0 = i0.x, b1 = i0.y, b2 = i0.z;
#pragma unroll
  for (int c = 1; c < 4; ++c) {
    float4 dc = ((const float4*)pd)[(size_t)c * 65536 + gq];
    int4 ic = ((const int4*)pi)[(size_t)c * 65536 + gq];
    float kv[3] = {dc.x, dc.y, dc.z};
    int jv[3] = {ic.x, ic.y, ic.z};
#pragma unroll
    for (int j = 0; j < 3; ++j) {
      float key = kv[j];
      int idx = jv[j];
      bool c0 = key < a0, c1 = key < a1, c2 = key < a2;
      a2 = c1 ? a1 : (c2 ? key : a2);
      b2 = c1 ? b1 : (c2 ? idx : b2);
      a1 = c0 ? a0 : (c1 ? key : a1);
      b1 = c0 ? b0 : (c1 ? idx : b1);
      a0 = c0 ? key : a0;
      b0 = c0 ? idx : b0;
    }
  }
  float v0 = 1.0f / a0, v1 = 1.0f / a1, v2 = 1.0f / a2;
  float s = 1.0f / (v0 + v1 + v2);
  int base = gq * 3;
  w_out[base + 0] = v0 * s;
  w_out[base + 1] = v1 * s;
  w_out[base + 2] = v2 * s;
  i_out[base + 0] = b0;
  i_out[base + 1] = b1;
  i_out[base + 2] = b2;
}

// ---------------------------------------------------------------------------
// Kernel 2: fp32 -> bf16 elementwise cast (for W1, W2).
// ---------------------------------------------------------------------------
__global__ __launch_bounds__(256) void cast_w_kernel(
    const float* __restrict__ src, u16* __restrict__ dst, int n) {
  int i = blockIdx.x * 256 + threadIdx.x;
  if (i < n) dst[i] = f2b(src[i]);
}

// ---------------------------------------------------------------------------
// Kernel 3: transpose-cast (B, C, P) fp32 -> (B, P, C) bf16 via LDS tile.
// ---------------------------------------------------------------------------
__global__ __launch_bounds__(256) void tcast_kernel(
    const float* __restrict__ in, u16* __restrict__ out, int C, int P) {
  __shared__ float tile[32][33];
  int tx = threadIdx.x & 31, ty = threadIdx.x >> 5;
  int p0 = blockIdx.x * 32, c0 = blockIdx.y * 32, b = blockIdx.z;
  const float* ib = in + (size_t)b * C * P;
  u16* ob = out + (size_t)b * P * C;
#pragma unroll
  for (int i = 0; i < 4; ++i)
    tile[ty + i * 8][tx] = ib[(size_t)(c0 + ty + i * 8) * P + p0 + tx];
  __syncthreads();
#pragma unroll
  for (int i = 0; i < 4; ++i)
    ob[(size_t)(p0 + ty + i * 8) * C + c0 + tx] = f2b(tile[tx][ty + i * 8]);
}

// ---------------------------------------------------------------------------
// MFMA GEMM: 128x128 tile, 4 waves 2x2, 4x4 mfma_f32_16x16x32_bf16 each.
//   NTILES>0: XCD-aware row-swizzle — batches {2k,2k+1} -> XCD k so the
//             INTERP gather's G slice (2 x 0.5MB bf16) is L2-resident.
//             NTILES = row-tiles-of-128 per batch; gridX = 16*NTILES (%8==0).
//   INTERP : acc += sum_j w3[row][j] * G_bf16[b*1024 + i3[row][j]][col]
//   STATS  : per-column sum/sumsq atomics into statsOut[0:256]/[256:512]
//   OUTB   : store bf16 (else fp32)
//   BNA    : A-staging applies BN(statsIn,gamma,beta)+ReLU (h1 -> a2 fused)
// ---------------------------------------------------------------------------
template <int K, int NTILES, bool INTERP, bool STATS, bool OUTB, bool BNA>
__global__ __launch_bounds__(256) void gemm_mfma(
    const u16* __restrict__ A, int lda, const u16* __restrict__ B, int ldb,
    void* __restrict__ out, const u16* __restrict__ G,
    const float* __restrict__ w3, const int* __restrict__ i3,
    float* __restrict__ statsOut, const float* __restrict__ statsIn,
    const float* __restrict__ gamma, const float* __restrict__ beta) {
  __shared__ u16 As[128 * 32];
  __shared__ u16 Bs[128 * 32];
  __shared__ float wsh[128][3];
  __shared__ int ish[128][3];
  __shared__ float scA[256], shA[256];

  int t = threadIdx.x;
  int w = t >> 6, l = t & 63;
  int n0;
  if (NTILES > 0) {
    int p = blockIdx.x;
    int batch = ((p & 7) << 1) | ((p >> 3) & 1);
    int nt = p >> 4;
    n0 = (batch * NTILES + nt) * 128;
  } else {
    n0 = blockIdx.x * 128;
  }
  int o0 = blockIdx.y * 128;

  if (INTERP) {
    for (int e = t; e < 384; e += 256) {
      int r = e / 3, j = e - 3 * r;
      wsh[r][j] = w3[(n0 + r) * 3 + j];
      ish[r][j] = i3[(n0 + r) * 3 + j];
    }
  }
  if (BNA) {
    float mean = statsIn[t] * INV_CNT;
    float var = statsIn[256 + t] * INV_CNT - mean * mean;
    float s = rsqrtf(var + EPSV) * gamma[t];
    scA[t] = s;
    shA[t] = beta[t] - mean * s;
  }

  int wm = w & 1, wn = w >> 1;
  int lr = l >> 2, lc = l & 3;
  int q = l >> 4, m = l & 15;

  f32x4 acc[4][4] = {};

  const u16* arow = A + (size_t)n0 * lda;
  const u16* brow = B + (size_t)o0 * ldb;

#pragma unroll
  for (int kt = 0; kt < K; kt += 32) {
    __syncthreads();
#pragma unroll
    for (int r = 0; r < 2; ++r) {
      int row = r * 64 + w * 16 + lr;
      if (BNA) {
        union { uint4 u; u16 s[8]; } v, o;
        v.u = *(const uint4*)(arow + (size_t)row * lda + kt + lc * 8);
        int cb = kt + lc * 8;
#pragma unroll
        for (int j = 0; j < 8; ++j) {
          float f = fmaf(b2f(v.s[j]), scA[cb + j], shA[cb + j]);
          o.s[j] = f2b(fmaxf(f, 0.0f));
        }
        *(uint4*)(As + row * 32 + lc * 8) = o.u;
      } else {
        GLD_LDS16(arow + (size_t)row * lda + kt + lc * 8, As + row * 32 + lc * 8);
      }
    }
#pragma unroll
    for (int r = 0; r < 2; ++r) {
      int row = r * 64 + w * 16 + lr;
      GLD_LDS16(brow + (size_t)row * ldb + kt + lc * 8, Bs + row * 32 + lc * 8);
    }
    __syncthreads();
    bf16x8 af[4], bf[4];
#pragma unroll
    for (int i = 0; i < 4; ++i)
      af[i] = *(const bf16x8*)(As + (wm * 64 + i * 16 + m) * 32 + q * 8);
#pragma unroll
    for (int j = 0; j < 4; ++j)
      bf[j] = *(const bf16x8*)(Bs + (wn * 64 + j * 16 + m) * 32 + q * 8);
#pragma unroll
    for (int i = 0; i < 4; ++i)
#pragma unroll
      for (int j = 0; j < 4; ++j)
        acc[i][j] =
            __builtin_amdgcn_mfma_f32_16x16x32_bf16(af[i], bf[j], acc[i][j], 0, 0, 0);
  }

  if (INTERP) {
    int b = n0 >> 12;
#pragma unroll
    for (int i = 0; i < 4; ++i) {
#pragma unroll
      for (int reg = 0; reg < 4; ++reg) {
        int rl = wm * 64 + i * 16 + q * 4 + reg;
        float w0 = wsh[rl][0], w1 = wsh[rl][1], w2 = wsh[rl][2];
        const u16* g0 = G + ((size_t)(b * 1024 + ish[rl][0])) * 256 + o0;
        const u16* g1 = G + ((size_t)(b * 1024 + ish[rl][1])) * 256 + o0;
        const u16* g2 = G + ((size_t)(b * 1024 + ish[rl][2])) * 256 + o0;
#pragma unroll
        for (int j = 0; j < 4; ++j) {
          int c = wn * 64 + j * 16 + m;
          acc[i][j][reg] +=
              w0 * b2f(g0[c]) + w1 * b2f(g1[c]) + w2 * b2f(g2[c]);
        }
      }
    }
  }

  if (STATS) {
#pragma unroll
    for (int j = 0; j < 4; ++j) {
      float s = 0.0f, ss = 0.0f;
#pragma unroll
      for (int i = 0; i < 4; ++i)
#pragma unroll
        for (int reg = 0; reg < 4; ++reg) {
          float v = acc[i][j][reg];
          s += v;
          ss += v * v;
        }
      s += __shfl_down(s, 32); ss += __shfl_down(ss, 32);
      s += __shfl_down(s, 16); ss += __shfl_down(ss, 16);
      if (l < 16) {
        int c = o0 + wn * 64 + j * 16 + l;
        atomicAdd(&statsOut[c], s);
        atomicAdd(&statsOut[256 + c], ss);
      }
    }
  }

#pragma unroll
  for (int i = 0; i < 4; ++i) {
    int gr = n0 + wm * 64 + i * 16 + q * 4;
#pragma unroll
    for (int reg = 0; reg < 4; ++reg) {
#pragma unroll
      for (int j = 0; j < 4; ++j) {
        int gc = o0 + wn * 64 + j * 16 + m;
        size_t off = (size_t)(gr + reg) * 256 + gc;
        if (OUTB)
          ((u16*)out)[off] = f2b(acc[i][j][reg]);
        else
          ((float*)out)[off] = acc[i][j][reg];
      }
    }
  }
}

// ---------------------------------------------------------------------------
// Kernel 6: BN2 + ReLU + transpose h2(bf16, B*N x 256) -> out fp32 (B,256,N).
// ---------------------------------------------------------------------------
__global__ __launch_bounds__(256) void bn2t_kernel(
    const u16* __restrict__ h2, const float* __restrict__ stats,
    const float* __restrict__ gamma, const float* __restrict__ beta,
    float* __restrict__ out) {
  __shared__ float tile[32][33];
  int tx = threadIdx.x & 31, ty = threadIdx.x >> 5;
  int n0 = blockIdx.x * 32, c0 = blockIdx.y * 32, b = blockIdx.z;
  int c = c0 + tx;
  float mean = stats[c] * INV_CNT;
  float var = stats[256 + c] * INV_CNT - mean * mean;
  float s = rsqrtf(var + EPSV) * gamma[c];
  float sh = beta[c] - mean * s;
#pragma unroll
  for (int i = 0; i < 4; ++i) {
    int n = n0 + ty + i * 8;
    float v = b2f(h2[((size_t)b * NN + n) * 256 + c]) * s + sh;
    tile[ty + i * 8][tx] = fmaxf(v, 0.0f);
  }
  __syncthreads();
#pragma unroll
  for (int i = 0; i < 4; ++i)
    out[((size_t)b * 256 + c0 + ty + i * 8) * NN + n0 + tx] = tile[tx][ty + i * 8];
}

// ---------------------------------------------------------------------------
// ws layout (bytes):
//   0        w3       786432
//   786432   i3       786432
//   1572864  stats    4096    (s1,q1,s2,q2)
//   1576960  W1b      196608
//   1773568  W2b      131072
//   1904640  p2t      8388608   \  pd (4.2MB) + pi (4.2MB) alias this region
//   10293248 p1t      16777216  /  during knn/merge (dead before tcast)
//   27070464 G(bf16)  8388608
//   43847680 h2b      33554432
// h1b (bf16) lives in d_out; gemm2 reads it (BN1 fused), bn2t overwrites.
// ---------------------------------------------------------------------------
extern "C" void kernel_launch(void* const* d_in, const int* in_sizes, int n_in,
                              void* d_out, int out_size, void* d_ws,
                              size_t ws_size, hipStream_t stream) {
  const float* xyz1    = (const float*)d_in[0];
  const float* xyz2    = (const float*)d_in[1];
  const float* points1 = (const float*)d_in[2];
  const float* points2 = (const float*)d_in[3];
  const float* W1      = (const float*)d_in[4];
  const float* gamma1  = (const float*)d_in[5];
  const float* beta1   = (const float*)d_in[6];
  const float* W2      = (const float*)d_in[7];
  const float* gamma2  = (const float*)d_in[8];
  const float* beta2   = (const float*)d_in[9];

  char* ws = (char*)d_ws;
  float* w3    = (float*)(ws + 0);
  int*   i3    = (int*)(ws + 786432);
  float* stats = (float*)(ws + 1572864);
  u16*   W1b   = (u16*)(ws + 1576960);
  u16*   W2b   = (u16*)(ws + 1773568);
  float* pd    = (float*)(ws + 1904640);
  int*   pi    = (int*)(ws + 1904640 + 4194304);
  u16*   p2t   = (u16*)(ws + 1904640);
  u16*   p1t   = (u16*)(ws + 10293248);
  u16*   G     = (u16*)(ws + 27070464);
  u16*   h2b   = (u16*)(ws + 43847680);
  u16*   h1b   = (u16*)d_out;
  float* out   = (float*)d_out;

  hipMemsetAsync(stats, 0, 4096, stream);
  knn_kernel<<<512, 256, 0, stream>>>(xyz1, xyz2, pd, pi);
  knn_merge<<<256, 256, 0, stream>>>(pd, pi, w3, i3);
  cast_w_kernel<<<384, 256, 0, stream>>>(W1, W1b, 98304);
  cast_w_kernel<<<256, 256, 0, stream>>>(W2, W2b, 65536);
  tcast_kernel<<<dim3(32, 8, 16), 256, 0, stream>>>(points2, p2t, C2V, MM);
  tcast_kernel<<<dim3(128, 4, 16), 256, 0, stream>>>(points1, p1t, C1V, NN);
  // G = p2^T * W1[:, 0:256]^T (bf16 out), XCD-swizzled: batch b on XCD b/2
  gemm_mfma<256, 8, false, false, true, false><<<dim3(128, 2), 256, 0, stream>>>(
      p2t, 256, W1b, 384, G, nullptr, nullptr, nullptr, nullptr, nullptr,
      nullptr, nullptr);
  // h1 = p1t * W1[:, 256:384]^T + interp(G); stats1 atomics; bf16 out
  gemm_mfma<128, 32, true, true, true, false><<<dim3(512, 2), 256, 0, stream>>>(
      p1t, 128, W1b + 256, 384, h1b, G, w3, i3, stats, nullptr, nullptr,
      nullptr);
  // h2 = relu(BN1(h1)) * W2^T with BN1 fused in A-staging; stats2 atomics
  gemm_mfma<256, 0, false, true, true, true><<<dim3(512, 2), 256, 0, stream>>>(
      h1b, 256, W2b, 256, h2b, nullptr, nullptr, nullptr, stats + 512, stats,
      gamma1, beta1);
  bn2t_kernel<<<dim3(128, 8, 16), 256, 0, stream>>>(h2b, stats + 512, gamma2,
                                                    beta2, out);
}

// Round 5
// 303.149 us; speedup vs baseline: 2.7912x; 1.0073x over previous
//
#include <hip/hip_runtime.h>

typedef unsigned short u16;
typedef unsigned int u32;

#define BB 16
#define NN 4096
#define MM 1024
#define C1V 128
#define C2V 256
#define O1 256
#define O2 256
#define EPSV 1e-5f
#define INV_CNT (1.0f/65536.0f)

typedef __attribute__((ext_vector_type(8))) short bf16x8;
typedef __attribute__((ext_vector_type(4))) float f32x4;

static __device__ __forceinline__ u16 f2b(float f) {
  u32 u = __float_as_uint(f);
  u32 r = (u + 0x7FFFu + ((u >> 16) & 1u)) >> 16;
  return (u16)r;
}
static __device__ __forceinline__ float b2f(u16 s) {
  return __uint_as_float(((u32)s) << 16);
}

// ---------------------------------------------------------------------------
// Kernel 1: 3-NN partials. Grid 512 = b(16) x qtile(8) x chunk(4).
// ---------------------------------------------------------------------------
__global__ __launch_bounds__(256) void knn_kernel(
    const float* __restrict__ xyz1, const float* __restrict__ xyz2,
    float* __restrict__ pd, int* __restrict__ pi) {
  __shared__ float4 cand[256];
  int bx = blockIdx.x;
  int c = bx & 3;
  int qt = (bx >> 2) & 7;
  int b = bx >> 5;
  int t = threadIdx.x;

  const float* x2b = xyz2 + b * 3 * MM;
  {
    float x = x2b[c * 256 + t];
    float y = x2b[MM + c * 256 + t];
    float z = x2b[2 * MM + c * 256 + t];
    cand[t] = make_float4(x, y, z, x * x + y * y + z * z);
  }
  __syncthreads();

  const float* x1b = xyz1 + b * 3 * NN;
  int n0 = qt * 512 + t;
  int n1 = n0 + 256;
  float px0 = x1b[n0], py0 = x1b[NN + n0], pz0 = x1b[2 * NN + n0];
  float px1 = x1b[n1], py1 = x1b[NN + n1], pz1 = x1b[2 * NN + n1];

  const float INF = 3.4e38f;
  float k00 = INF, k01 = INF, k02 = INF;
  float k10 = INF, k11 = INF, k12 = INF;
  int j00 = 0, j01 = 0, j02 = 0;
  int j10 = 0, j11 = 0, j12 = 0;

#pragma unroll 8
  for (int m = 0; m < 256; ++m) {
    float4 cd = cand[m];
    {
      float dot = fmaf(px0, cd.x, fmaf(py0, cd.y, pz0 * cd.z));
      float key = fmaf(-2.0f, dot, cd.w);
      bool c0 = key < k00, c1 = key < k01, c2 = key < k02;
      k02 = c1 ? k01 : (c2 ? key : k02);
      j02 = c1 ? j01 : (c2 ? m : j02);
      k01 = c0 ? k00 : (c1 ? key : k01);
      j01 = c0 ? j00 : (c1 ? m : j01);
      k00 = c0 ? key : k00;
      j00 = c0 ? m : j00;
    }
    {
      float dot = fmaf(px1, cd.x, fmaf(py1, cd.y, pz1 * cd.z));
      float key = fmaf(-2.0f, dot, cd.w);
      bool c0 = key < k10, c1 = key < k11, c2 = key < k12;
      k12 = c1 ? k11 : (c2 ? key : k12);
      j12 = c1 ? j11 : (c2 ? m : j12);
      k11 = c0 ? k10 : (c1 ? key : k11);
      j11 = c0 ? j10 : (c1 ? m : j11);
      k10 = c0 ? key : k10;
      j10 = c0 ? m : j10;
    }
  }

  float pn0 = px0 * px0 + py0 * py0 + pz0 * pz0;
  float pn1 = px1 * px1 + py1 * py1 + pz1 * pz1;
  int gq0 = b * NN + n0;
  int gq1 = b * NN + n1;
  int base = c << 8;
  ((float4*)pd)[(size_t)c * 65536 + gq0] =
      make_float4(fmaxf(k00 + pn0, 1e-10f), fmaxf(k01 + pn0, 1e-10f),
                  fmaxf(k02 + pn0, 1e-10f), 0.0f);
  ((int4*)pi)[(size_t)c * 65536 + gq0] =
      make_int4(base + j00, base + j01, base + j02, 0);
  ((float4*)pd)[(size_t)c * 65536 + gq1] =
      make_float4(fmaxf(k10 + pn1, 1e-10f), fmaxf(k11 + pn1, 1e-10f),
                  fmaxf(k12 + pn1, 1e-10f), 0.0f);
  ((int4*)pi)[(size_t)c * 65536 + gq1] =
      make_int4(base + j10, base + j11, base + j12, 0);
}

// ---------------------------------------------------------------------------
// Kernel 1b: merge 4 chunk top-3s -> final top-3, inverse-distance weights.
// ---------------------------------------------------------------------------
__global__ __launch_bounds__(256) void knn_merge(
    const float* __restrict__ pd, const int* __restrict__ pi,
    float* __restrict__ w_out, int* __restrict__ i_out) {
  int gq = blockIdx.x * 256 + threadIdx.x;
  float4 d0 = ((const float4*)pd)[gq];
  int4 i0 = ((const int4*)pi)[gq];
  float a0 = d0.x, a1 = d0.y, a2 = d0.z;
  int b0 = i0.x, b1 = i0.y, b2 = i0.z;
#pragma unroll
  for (int c = 1; c < 4; ++c) {
    float4 dc = ((const float4*)pd)[(size_t)c * 65536 + gq];
    int4 ic = ((const int4*)pi)[(size_t)c * 65536 + gq];
    float kv[3] = {dc.x, dc.y, dc.z};
    int jv[3] = {ic.x, ic.y, ic.z};
#pragma unroll
    for (int j = 0; j < 3; ++j) {
      float key = kv[j];
      int idx = jv[j];
      bool c0 = key < a0, c1 = key < a1, c2 = key < a2;
      a2 = c1 ? a1 : (c2 ? key : a2);
      b2 = c1 ? b1 : (c2 ? idx : b2);
      a1 = c0 ? a0 : (c1 ? key : a1);
      b1 = c0 ? b0 : (c1 ? idx : b1);
      a0 = c0 ? key : a0;
      b0 = c0 ? idx : b0;
    }
  }
  float v0 = 1.0f / a0, v1 = 1.0f / a1, v2 = 1.0f / a2;
  float s = 1.0f / (v0 + v1 + v2);
  int base = gq * 3;
  w_out[base + 0] = v0 * s;
  w_out[base + 1] = v1 * s;
  w_out[base + 2] = v2 * s;
  i_out[base + 0] = b0;
  i_out[base + 1] = b1;
  i_out[base + 2] = b2;
}

// ---------------------------------------------------------------------------
// Kernel 2: fp32 -> bf16 elementwise cast (for W1, W2).
// ---------------------------------------------------------------------------
__global__ __launch_bounds__(256) void cast_w_kernel(
    const float* __restrict__ src, u16* __restrict__ dst, int n) {
  int i = blockIdx.x * 256 + threadIdx.x;
  if (i < n) dst[i] = f2b(src[i]);
}

// ---------------------------------------------------------------------------
// Kernel 3: transpose-cast (B, C, P) fp32 -> (B, P, C) bf16 via LDS tile.
// ---------------------------------------------------------------------------
__global__ __launch_bounds__(256) void tcast_kernel(
    const float* __restrict__ in, u16* __restrict__ out, int C, int P) {
  __shared__ float tile[32][33];
  int tx = threadIdx.x & 31, ty = threadIdx.x >> 5;
  int p0 = blockIdx.x * 32, c0 = blockIdx.y * 32, b = blockIdx.z;
  const float* ib = in + (size_t)b * C * P;
  u16* ob = out + (size_t)b * P * C;
#pragma unroll
  for (int i = 0; i < 4; ++i)
    tile[ty + i * 8][tx] = ib[(size_t)(c0 + ty + i * 8) * P + p0 + tx];
  __syncthreads();
#pragma unroll
  for (int i = 0; i < 4; ++i)
    ob[(size_t)(p0 + ty + i * 8) * C + c0 + tx] = f2b(tile[tx][ty + i * 8]);
}

// ---------------------------------------------------------------------------
// MFMA GEMM, register-double-buffered K-loop with raw s_barrier (no vmcnt(0)
// drain): A/B tiles loaded to uint4 regs, iter k+1's loads issued during
// iter k, ds_write waits are the compiler's fine-grained vmcnt. 2 LDS buffers.
//   NTILES>0: XCD-aware row-swizzle (batches {2k,2k+1} -> XCD k).
//   INTERP : post-loop, build combined interp tile (sum_j w_j * G[idx_j]) in
//            LDS via bf16x8 16B gathers (24 wide loads/thread), then per-lane
//            C-layout add from LDS.
//   STATS  : per-column sum/sumsq atomics.  OUTB: bf16 store.
//   BNA    : A-staging applies BN(statsIn)+ReLU between reg load and ds_write.
// ---------------------------------------------------------------------------
template <int K, int NTILES, bool INTERP, bool STATS, bool OUTB, bool BNA>
__global__ __launch_bounds__(256) void gemm_mfma(
    const u16* __restrict__ A, int lda, const u16* __restrict__ B, int ldb,
    void* __restrict__ out, const u16* __restrict__ G,
    const float* __restrict__ w3, const int* __restrict__ i3,
    float* __restrict__ statsOut, const float* __restrict__ statsIn,
    const float* __restrict__ gamma, const float* __restrict__ beta) {
  __shared__ u16 smem[16384];  // As0|As1|Bs0|Bs1 (4x8KB); reused as interp tile
  __shared__ float wsh[128][3];
  __shared__ int ish[128][3];
  __shared__ float scA[256], shA[256];

  int t = threadIdx.x;
  int w = t >> 6, l = t & 63;
  int n0;
  if (NTILES > 0) {
    int p = blockIdx.x;
    int batch = ((p & 7) << 1) | ((p >> 3) & 1);
    int nt = p >> 4;
    n0 = (batch * NTILES + nt) * 128;
  } else {
    n0 = blockIdx.x * 128;
  }
  int o0 = blockIdx.y * 128;

  if (INTERP) {
    for (int e = t; e < 384; e += 256) {
      int r = e / 3, j = e - 3 * r;
      wsh[r][j] = w3[(n0 + r) * 3 + j];
      ish[r][j] = i3[(n0 + r) * 3 + j];
    }
  }
  if (BNA) {
    float mean = statsIn[t] * INV_CNT;
    float var = statsIn[256 + t] * INV_CNT - mean * mean;
    float s = rsqrtf(var + EPSV) * gamma[t];
    scA[t] = s;
    shA[t] = beta[t] - mean * s;
  }
  if (INTERP || BNA) __syncthreads();

  int wm = w & 1, wn = w >> 1;
  int lr = l >> 2, lc = l & 3;  // staging: row-in-16, 16B chunk
  int q = l >> 4, m = l & 15;   // mfma lane decomposition

  const u16* aptr0 = A + (size_t)(n0 + w * 16 + lr) * lda + lc * 8;
  const u16* aptr1 = aptr0 + (size_t)64 * lda;
  const u16* bptr0 = B + (size_t)(o0 + w * 16 + lr) * ldb + lc * 8;
  const u16* bptr1 = bptr0 + (size_t)64 * ldb;
  int sidx = (w * 16 + lr) * 32 + lc * 8;  // LDS staging offset (row*32+chunk)

  uint4 ra0 = *(const uint4*)(aptr0);
  uint4 ra1 = *(const uint4*)(aptr1);
  uint4 rb0 = *(const uint4*)(bptr0);
  uint4 rb1 = *(const uint4*)(bptr1);

  f32x4 acc[4][4] = {};
  constexpr int NIT = K / 32;

#pragma unroll
  for (int it = 0; it < NIT; ++it) {
    u16* as = smem + (it & 1) * 4096;
    u16* bs = smem + 8192 + (it & 1) * 4096;
    if (BNA) {
      int cb = it * 32 + lc * 8;
      union { uint4 u; u16 s[8]; } v, o;
      v.u = ra0;
#pragma unroll
      for (int j = 0; j < 8; ++j)
        o.s[j] = f2b(fmaxf(fmaf(b2f(v.s[j]), scA[cb + j], shA[cb + j]), 0.0f));
      *(uint4*)(as + sidx) = o.u;
      v.u = ra1;
#pragma unroll
      for (int j = 0; j < 8; ++j)
        o.s[j] = f2b(fmaxf(fmaf(b2f(v.s[j]), scA[cb + j], shA[cb + j]), 0.0f));
      *(uint4*)(as + sidx + 64 * 32) = o.u;
    } else {
      *(uint4*)(as + sidx) = ra0;
      *(uint4*)(as + sidx + 64 * 32) = ra1;
    }
    *(uint4*)(bs + sidx) = rb0;
    *(uint4*)(bs + sidx + 64 * 32) = rb1;
    if (it + 1 < NIT) {  // prefetch next tile into regs (lands ~next iter)
      int kt = (it + 1) * 32;
      ra0 = *(const uint4*)(aptr0 + kt);
      ra1 = *(const uint4*)(aptr1 + kt);
      rb0 = *(const uint4*)(bptr0 + kt);
      rb1 = *(const uint4*)(bptr1 + kt);
    }
    asm volatile("s_waitcnt lgkmcnt(0)" ::: "memory");
    __builtin_amdgcn_s_barrier();
    asm volatile("" ::: "memory");
    bf16x8 af[4], bf[4];
#pragma unroll
    for (int i = 0; i < 4; ++i)
      af[i] = *(const bf16x8*)(as + (wm * 64 + i * 16 + m) * 32 + q * 8);
#pragma unroll
    for (int j = 0; j < 4; ++j)
      bf[j] = *(const bf16x8*)(bs + (wn * 64 + j * 16 + m) * 32 + q * 8);
#pragma unroll
    for (int i = 0; i < 4; ++i)
#pragma unroll
      for (int j = 0; j < 4; ++j)
        acc[i][j] =
            __builtin_amdgcn_mfma_f32_16x16x32_bf16(af[i], bf[j], acc[i][j], 0, 0, 0);
    asm volatile("" ::: "memory");
    __builtin_amdgcn_s_barrier();
    asm volatile("" ::: "memory");
  }

  if (INTERP) {
    __syncthreads();  // smem (As/Bs) dead; reuse as 128x128 bf16 interp tile
    int b = n0 >> 12;
    int rl = t >> 1, half = t & 1;
    float w0 = wsh[rl][0], w1 = wsh[rl][1], w2 = wsh[rl][2];
    const u16* g0 = G + ((size_t)(b * 1024 + ish[rl][0])) * 256 + o0 + half * 64;
    const u16* g1 = G + ((size_t)(b * 1024 + ish[rl][1])) * 256 + o0 + half * 64;
    const u16* g2 = G + ((size_t)(b * 1024 + ish[rl][2])) * 256 + o0 + half * 64;
    u16* dst = smem + rl * 128 + half * 64;
#pragma unroll
    for (int c8 = 0; c8 < 8; ++c8) {
      bf16x8 v0 = *(const bf16x8*)(g0 + c8 * 8);
      bf16x8 v1 = *(const bf16x8*)(g1 + c8 * 8);
      bf16x8 v2 = *(const bf16x8*)(g2 + c8 * 8);
      union { uint4 u; u16 s[8]; } o;
#pragma unroll
      for (int e = 0; e < 8; ++e) {
        float f = w0 * b2f((u16)v0[e]) + w1 * b2f((u16)v1[e]) +
                  w2 * b2f((u16)v2[e]);
        o.s[e] = f2b(f);
      }
      *(uint4*)(dst + c8 * 8) = o.u;
    }
    __syncthreads();
#pragma unroll
    for (int i = 0; i < 4; ++i)
#pragma unroll
      for (int reg = 0; reg < 4; ++reg) {
        int row = wm * 64 + i * 16 + q * 4 + reg;
#pragma unroll
        for (int j = 0; j < 4; ++j) {
          int col = wn * 64 + j * 16 + m;
          acc[i][j][reg] += b2f(smem[row * 128 + col]);
        }
      }
  }

  if (STATS) {
#pragma unroll
    for (int j = 0; j < 4; ++j) {
      float s = 0.0f, ss = 0.0f;
#pragma unroll
      for (int i = 0; i < 4; ++i)
#pragma unroll
        for (int reg = 0; reg < 4; ++reg) {
          float v = acc[i][j][reg];
          s += v;
          ss += v * v;
        }
      s += __shfl_down(s, 32); ss += __shfl_down(ss, 32);
      s += __shfl_down(s, 16); ss += __shfl_down(ss, 16);
      if (l < 16) {
        int c = o0 + wn * 64 + j * 16 + l;
        atomicAdd(&statsOut[c], s);
        atomicAdd(&statsOut[256 + c], ss);
      }
    }
  }

#pragma unroll
  for (int i = 0; i < 4; ++i) {
    int gr = n0 + wm * 64 + i * 16 + q * 4;
#pragma unroll
    for (int reg = 0; reg < 4; ++reg) {
#pragma unroll
      for (int j = 0; j < 4; ++j) {
        int gc = o0 + wn * 64 + j * 16 + m;
        size_t off = (size_t)(gr + reg) * 256 + gc;
        if (OUTB)
          ((u16*)out)[off] = f2b(acc[i][j][reg]);
        else
          ((float*)out)[off] = acc[i][j][reg];
      }
    }
  }
}

// ---------------------------------------------------------------------------
// Kernel 6: BN2 + ReLU + transpose h2(bf16, B*N x 256) -> out fp32 (B,256,N).
// ---------------------------------------------------------------------------
__global__ __launch_bounds__(256) void bn2t_kernel(
    const u16* __restrict__ h2, const float* __restrict__ stats,
    const float* __restrict__ gamma, const float* __restrict__ beta,
    float* __restrict__ out) {
  __shared__ float tile[32][33];
  int tx = threadIdx.x & 31, ty = threadIdx.x >> 5;
  int n0 = blockIdx.x * 32, c0 = blockIdx.y * 32, b = blockIdx.z;
  int c = c0 + tx;
  float mean = stats[c] * INV_CNT;
  float var = stats[256 + c] * INV_CNT - mean * mean;
  float s = rsqrtf(var + EPSV) * gamma[c];
  float sh = beta[c] - mean * s;
#pragma unroll
  for (int i = 0; i < 4; ++i) {
    int n = n0 + ty + i * 8;
    float v = b2f(h2[((size_t)b * NN + n) * 256 + c]) * s + sh;
    tile[ty + i * 8][tx] = fmaxf(v, 0.0f);
  }
  __syncthreads();
#pragma unroll
  for (int i = 0; i < 4; ++i)
    out[((size_t)b * 256 + c0 + ty + i * 8) * NN + n0 + tx] = tile[tx][ty + i * 8];
}

// ---------------------------------------------------------------------------
// ws layout (bytes):
//   0        w3       786432
//   786432   i3       786432
//   1572864  stats    4096    (s1,q1,s2,q2)
//   1576960  W1b      196608
//   1773568  W2b      131072
//   1904640  p2t      8388608   \  pd (4.2MB) + pi (4.2MB) alias this region
//   10293248 p1t      16777216  /  during knn/merge (dead before tcast)
//   27070464 G(bf16)  8388608
//   43847680 h2b      33554432
// h1b (bf16) lives in d_out; gemm2 reads it (BN1 fused), bn2t overwrites.
// ---------------------------------------------------------------------------
extern "C" void kernel_launch(void* const* d_in, const int* in_sizes, int n_in,
                              void* d_out, int out_size, void* d_ws,
                              size_t ws_size, hipStream_t stream) {
  const float* xyz1    = (const float*)d_in[0];
  const float* xyz2    = (const float*)d_in[1];
  const float* points1 = (const float*)d_in[2];
  const float* points2 = (const float*)d_in[3];
  const float* W1      = (const float*)d_in[4];
  const float* gamma1  = (const float*)d_in[5];
  const float* beta1   = (const float*)d_in[6];
  const float* W2      = (const float*)d_in[7];
  const float* gamma2  = (const float*)d_in[8];
  const float* beta2   = (const float*)d_in[9];

  char* ws = (char*)d_ws;
  float* w3    = (float*)(ws + 0);
  int*   i3    = (int*)(ws + 786432);
  float* stats = (float*)(ws + 1572864);
  u16*   W1b   = (u16*)(ws + 1576960);
  u16*   W2b   = (u16*)(ws + 1773568);
  float* pd    = (float*)(ws + 1904640);
  int*   pi    = (int*)(ws + 1904640 + 4194304);
  u16*   p2t   = (u16*)(ws + 1904640);
  u16*   p1t   = (u16*)(ws + 10293248);
  u16*   G     = (u16*)(ws + 27070464);
  u16*   h2b   = (u16*)(ws + 43847680);
  u16*   h1b   = (u16*)d_out;
  float* out   = (float*)d_out;

  hipMemsetAsync(stats, 0, 4096, stream);
  knn_kernel<<<512, 256, 0, stream>>>(xyz1, xyz2, pd, pi);
  knn_merge<<<256, 256, 0, stream>>>(pd, pi, w3, i3);
  cast_w_kernel<<<384, 256, 0, stream>>>(W1, W1b, 98304);
  cast_w_kernel<<<256, 256, 0, stream>>>(W2, W2b, 65536);
  tcast_kernel<<<dim3(32, 8, 16), 256, 0, stream>>>(points2, p2t, C2V, MM);
  tcast_kernel<<<dim3(128, 4, 16), 256, 0, stream>>>(points1, p1t, C1V, NN);
  // G = p2^T * W1[:, 0:256]^T (bf16 out), XCD-swizzled: batch b on XCD b/2
  gemm_mfma<256, 8, false, false, true, false><<<dim3(128, 2), 256, 0, stream>>>(
      p2t, 256, W1b, 384, G, nullptr, nullptr, nullptr, nullptr, nullptr,
      nullptr, nullptr);
  // h1 = p1t * W1[:, 256:384]^T + interp(G); stats1 atomics; bf16 out
  gemm_mfma<128, 32, true, true, true, false><<<dim3(512, 2), 256, 0, stream>>>(
      p1t, 128, W1b + 256, 384, h1b, G, w3, i3, stats, nullptr, nullptr,
      nullptr);
  // h2 = relu(BN1(h1)) * W2^T with BN1 fused in A-staging; stats2 atomics
  gemm_mfma<256, 0, false, true, true, true><<<dim3(512, 2), 256, 0, stream>>>(
      h1b, 256, W2b, 256, h2b, nullptr, nullptr, nullptr, stats + 512, stats,
      gamma1, beta1);
  bn2t_kernel<<<dim3(128, 8, 16), 256, 0, stream>>>(h2b, stats + 512, gamma2,
                                                    beta2, out);
}

// Round 6
// 257.757 us; speedup vs baseline: 3.2828x; 1.1761x over previous
//
#include <hip/hip_runtime.h>

typedef unsigned short u16;
typedef unsigned int u32;

#define BB 16
#define NN 4096
#define MM 1024
#define C1V 128
#define C2V 256
#define O1 256
#define O2 256
#define EPSV 1e-5f
#define INV_CNT (1.0f/65536.0f)
#define NREP 32  // stats atomic replicas: contention/address 1024 -> 32

typedef __attribute__((ext_vector_type(8))) short bf16x8;
typedef __attribute__((ext_vector_type(4))) float f32x4;

static __device__ __forceinline__ u16 f2b(float f) {
  u32 u = __float_as_uint(f);
  u32 r = (u + 0x7FFFu + ((u >> 16) & 1u)) >> 16;
  return (u16)r;
}
static __device__ __forceinline__ float b2f(u16 s) {
  return __uint_as_float(((u32)s) << 16);
}

#define GLD_LDS16(gp, lp)                                                      \
  __builtin_amdgcn_global_load_lds(                                            \
      (const __attribute__((address_space(1))) void*)(gp),                     \
      (__attribute__((address_space(3))) void*)(lp), 16, 0, 0)

// ---------------------------------------------------------------------------
// Kernel 1: 3-NN partials. Grid 512 = b(16) x qtile(8) x chunk(4).
// ---------------------------------------------------------------------------
__global__ __launch_bounds__(256) void knn_kernel(
    const float* __restrict__ xyz1, const float* __restrict__ xyz2,
    float* __restrict__ pd, int* __restrict__ pi) {
  __shared__ float4 cand[256];
  int bx = blockIdx.x;
  int c = bx & 3;
  int qt = (bx >> 2) & 7;
  int b = bx >> 5;
  int t = threadIdx.x;

  const float* x2b = xyz2 + b * 3 * MM;
  {
    float x = x2b[c * 256 + t];
    float y = x2b[MM + c * 256 + t];
    float z = x2b[2 * MM + c * 256 + t];
    cand[t] = make_float4(x, y, z, x * x + y * y + z * z);
  }
  __syncthreads();

  const float* x1b = xyz1 + b * 3 * NN;
  int n0 = qt * 512 + t;
  int n1 = n0 + 256;
  float px0 = x1b[n0], py0 = x1b[NN + n0], pz0 = x1b[2 * NN + n0];
  float px1 = x1b[n1], py1 = x1b[NN + n1], pz1 = x1b[2 * NN + n1];

  const float INF = 3.4e38f;
  float k00 = INF, k01 = INF, k02 = INF;
  float k10 = INF, k11 = INF, k12 = INF;
  int j00 = 0, j01 = 0, j02 = 0;
  int j10 = 0, j11 = 0, j12 = 0;

#pragma unroll 8
  for (int m = 0; m < 256; ++m) {
    float4 cd = cand[m];
    {
      float dot = fmaf(px0, cd.x, fmaf(py0, cd.y, pz0 * cd.z));
      float key = fmaf(-2.0f, dot, cd.w);
      bool c0 = key < k00, c1 = key < k01, c2 = key < k02;
      k02 = c1 ? k01 : (c2 ? key : k02);
      j02 = c1 ? j01 : (c2 ? m : j02);
      k01 = c0 ? k00 : (c1 ? key : k01);
      j01 = c0 ? j00 : (c1 ? m : j01);
      k00 = c0 ? key : k00;
      j00 = c0 ? m : j00;
    }
    {
      float dot = fmaf(px1, cd.x, fmaf(py1, cd.y, pz1 * cd.z));
      float key = fmaf(-2.0f, dot, cd.w);
      bool c0 = key < k10, c1 = key < k11, c2 = key < k12;
      k12 = c1 ? k11 : (c2 ? key : k12);
      j12 = c1 ? j11 : (c2 ? m : j12);
      k11 = c0 ? k10 : (c1 ? key : k11);
      j11 = c0 ? j10 : (c1 ? m : j11);
      k10 = c0 ? key : k10;
      j10 = c0 ? m : j10;
    }
  }

  float pn0 = px0 * px0 + py0 * py0 + pz0 * pz0;
  float pn1 = px1 * px1 + py1 * py1 + pz1 * pz1;
  int gq0 = b * NN + n0;
  int gq1 = b * NN + n1;
  int base = c << 8;
  ((float4*)pd)[(size_t)c * 65536 + gq0] =
      make_float4(fmaxf(k00 + pn0, 1e-10f), fmaxf(k01 + pn0, 1e-10f),
                  fmaxf(k02 + pn0, 1e-10f), 0.0f);
  ((int4*)pi)[(size_t)c * 65536 + gq0] =
      make_int4(base + j00, base + j01, base + j02, 0);
  ((float4*)pd)[(size_t)c * 65536 + gq1] =
      make_float4(fmaxf(k10 + pn1, 1e-10f), fmaxf(k11 + pn1, 1e-10f),
                  fmaxf(k12 + pn1, 1e-10f), 0.0f);
  ((int4*)pi)[(size_t)c * 65536 + gq1] =
      make_int4(base + j10, base + j11, base + j12, 0);
}

// ---------------------------------------------------------------------------
// Kernel 1b: merge 4 chunk top-3s -> final top-3, inverse-distance weights.
// ---------------------------------------------------------------------------
__global__ __launch_bounds__(256) void knn_merge(
    const float* __restrict__ pd, const int* __restrict__ pi,
    float* __restrict__ w_out, int* __restrict__ i_out) {
  int gq = blockIdx.x * 256 + threadIdx.x;
  float4 d0 = ((const float4*)pd)[gq];
  int4 i0 = ((const int4*)pi)[gq];
  float a0 = d0.x, a1 = d0.y, a2 = d0.z;
  int b0 = i0.x, b1 = i0.y, b2 = i0.z;
#pragma unroll
  for (int c = 1; c < 4; ++c) {
    float4 dc = ((const float4*)pd)[(size_t)c * 65536 + gq];
    int4 ic = ((const int4*)pi)[(size_t)c * 65536 + gq];
    float kv[3] = {dc.x, dc.y, dc.z};
    int jv[3] = {ic.x, ic.y, ic.z};
#pragma unroll
    for (int j = 0; j < 3; ++j) {
      float key = kv[j];
      int idx = jv[j];
      bool c0 = key < a0, c1 = key < a1, c2 = key < a2;
      a2 = c1 ? a1 : (c2 ? key : a2);
      b2 = c1 ? b1 : (c2 ? idx : b2);
      a1 = c0 ? a0 : (c1 ? key : a1);
      b1 = c0 ? b0 : (c1 ? idx : b1);
      a0 = c0 ? key : a0;
      b0 = c0 ? idx : b0;
    }
  }
  float v0 = 1.0f / a0, v1 = 1.0f / a1, v2 = 1.0f / a2;
  float s = 1.0f / (v0 + v1 + v2);
  int base = gq * 3;
  w_out[base + 0] = v0 * s;
  w_out[base + 1] = v1 * s;
  w_out[base + 2] = v2 * s;
  i_out[base + 0] = b0;
  i_out[base + 1] = b1;
  i_out[base + 2] = b2;
}

// ---------------------------------------------------------------------------
// Kernel 2: fp32 -> bf16 elementwise cast (for W1, W2).
// ---------------------------------------------------------------------------
__global__ __launch_bounds__(256) void cast_w_kernel(
    const float* __restrict__ src, u16* __restrict__ dst, int n) {
  int i = blockIdx.x * 256 + threadIdx.x;
  if (i < n) dst[i] = f2b(src[i]);
}

// ---------------------------------------------------------------------------
// Kernel 3: transpose-cast (B, C, P) fp32 -> (B, P, C) bf16 via LDS tile.
// ---------------------------------------------------------------------------
__global__ __launch_bounds__(256) void tcast_kernel(
    const float* __restrict__ in, u16* __restrict__ out, int C, int P) {
  __shared__ float tile[32][33];
  int tx = threadIdx.x & 31, ty = threadIdx.x >> 5;
  int p0 = blockIdx.x * 32, c0 = blockIdx.y * 32, b = blockIdx.z;
  const float* ib = in + (size_t)b * C * P;
  u16* ob = out + (size_t)b * P * C;
#pragma unroll
  for (int i = 0; i < 4; ++i)
    tile[ty + i * 8][tx] = ib[(size_t)(c0 + ty + i * 8) * P + p0 + tx];
  __syncthreads();
#pragma unroll
  for (int i = 0; i < 4; ++i)
    ob[(size_t)(p0 + ty + i * 8) * C + c0 + tx] = f2b(tile[tx][ty + i * 8]);
}

// ---------------------------------------------------------------------------
// Kernel 4: collapse NREP stats replicas -> compact [512] (sums, sumsqs).
// ---------------------------------------------------------------------------
__global__ __launch_bounds__(512) void stats_finalize(
    const float* __restrict__ R, float* __restrict__ outS) {
  int u = threadIdx.x;
  float s = 0.0f;
#pragma unroll
  for (int r = 0; r < NREP; ++r) s += R[r * 512 + u];
  outS[u] = s;
}

// ---------------------------------------------------------------------------
// MFMA GEMM: 128x128 tile, 4 waves 2x2, 4x4 mfma_f32_16x16x32_bf16 each.
// Round-4 K-loop (global_load_lds, single LDS buffer).
//   NTILES>0: XCD-aware row-swizzle (batches {2k,2k+1} -> XCD k).
//   INTERP : post-loop, build combined interp tile (sum_j w_j * G[idx_j]) in
//            LDS (full 32KB smem) via bf16x8 16B gathers, then per-lane add.
//   STATS  : per-column sum/sumsq atomics into replica (blockIdx.x & 31).
//   OUTB   : bf16 store.   BNA: A-staging applies BN(sum of replicas)+ReLU.
// ---------------------------------------------------------------------------
template <int K, int NTILES, bool INTERP, bool STATS, bool OUTB, bool BNA>
__global__ __launch_bounds__(256) void gemm_mfma(
    const u16* __restrict__ A, int lda, const u16* __restrict__ B, int ldb,
    void* __restrict__ out, const u16* __restrict__ G,
    const float* __restrict__ w3, const int* __restrict__ i3,
    float* __restrict__ statsOut, const float* __restrict__ statsInR,
    const float* __restrict__ gamma, const float* __restrict__ beta) {
  __shared__ u16 smem[16384];  // K-loop: As[0,4096) Bs[4096,8192); interp: all
  __shared__ float wsh[128][3];
  __shared__ int ish[128][3];
  __shared__ float scA[256], shA[256];

  int t = threadIdx.x;
  int w = t >> 6, l = t & 63;
  int n0;
  if (NTILES > 0) {
    int p = blockIdx.x;
    int batch = ((p & 7) << 1) | ((p >> 3) & 1);
    int nt = p >> 4;
    n0 = (batch * NTILES + nt) * 128;
  } else {
    n0 = blockIdx.x * 128;
  }
  int o0 = blockIdx.y * 128;

  if (INTERP) {
    for (int e = t; e < 384; e += 256) {
      int r = e / 3, j = e - 3 * r;
      wsh[r][j] = w3[(n0 + r) * 3 + j];
      ish[r][j] = i3[(n0 + r) * 3 + j];
    }
  }
  if (BNA) {
    float s = 0.0f, qq = 0.0f;
#pragma unroll
    for (int r = 0; r < NREP; ++r) {
      s += statsInR[r * 512 + t];
      qq += statsInR[r * 512 + 256 + t];
    }
    float mean = s * INV_CNT;
    float var = qq * INV_CNT - mean * mean;
    float sc = rsqrtf(var + EPSV) * gamma[t];
    scA[t] = sc;
    shA[t] = beta[t] - mean * sc;
  }

  int wm = w & 1, wn = w >> 1;
  int lr = l >> 2, lc = l & 3;  // staging: row-in-16, 16B chunk
  int q = l >> 4, m = l & 15;   // mfma lane decomposition

  f32x4 acc[4][4] = {};
  u16* As = smem;
  u16* Bs = smem + 4096;

  const u16* arow = A + (size_t)n0 * lda;
  const u16* brow = B + (size_t)o0 * ldb;

#pragma unroll
  for (int kt = 0; kt < K; kt += 32) {
    __syncthreads();
#pragma unroll
    for (int r = 0; r < 2; ++r) {
      int row = r * 64 + w * 16 + lr;
      if (BNA) {
        union { uint4 u; u16 s[8]; } v, o;
        v.u = *(const uint4*)(arow + (size_t)row * lda + kt + lc * 8);
        int cb = kt + lc * 8;
#pragma unroll
        for (int j = 0; j < 8; ++j) {
          float f = fmaf(b2f(v.s[j]), scA[cb + j], shA[cb + j]);
          o.s[j] = f2b(fmaxf(f, 0.0f));
        }
        *(uint4*)(As + row * 32 + lc * 8) = o.u;
      } else {
        GLD_LDS16(arow + (size_t)row * lda + kt + lc * 8, As + row * 32 + lc * 8);
      }
    }
#pragma unroll
    for (int r = 0; r < 2; ++r) {
      int row = r * 64 + w * 16 + lr;
      GLD_LDS16(brow + (size_t)row * ldb + kt + lc * 8, Bs + row * 32 + lc * 8);
    }
    __syncthreads();
    bf16x8 af[4], bf[4];
#pragma unroll
    for (int i = 0; i < 4; ++i)
      af[i] = *(const bf16x8*)(As + (wm * 64 + i * 16 + m) * 32 + q * 8);
#pragma unroll
    for (int j = 0; j < 4; ++j)
      bf[j] = *(const bf16x8*)(Bs + (wn * 64 + j * 16 + m) * 32 + q * 8);
#pragma unroll
    for (int i = 0; i < 4; ++i)
#pragma unroll
      for (int j = 0; j < 4; ++j)
        acc[i][j] =
            __builtin_amdgcn_mfma_f32_16x16x32_bf16(af[i], bf[j], acc[i][j], 0, 0, 0);
  }

  if (INTERP) {
    __syncthreads();  // As/Bs dead; reuse full smem as 128x128 bf16 tile
    int b = n0 >> 12;
    int rl = t >> 1, half = t & 1;
    float w0 = wsh[rl][0], w1 = wsh[rl][1], w2 = wsh[rl][2];
    const u16* g0 = G + ((size_t)(b * 1024 + ish[rl][0])) * 256 + o0 + half * 64;
    const u16* g1 = G + ((size_t)(b * 1024 + ish[rl][1])) * 256 + o0 + half * 64;
    const u16* g2 = G + ((size_t)(b * 1024 + ish[rl][2])) * 256 + o0 + half * 64;
    u16* dst = smem + rl * 128 + half * 64;
#pragma unroll
    for (int c8 = 0; c8 < 8; ++c8) {
      bf16x8 v0 = *(const bf16x8*)(g0 + c8 * 8);
      bf16x8 v1 = *(const bf16x8*)(g1 + c8 * 8);
      bf16x8 v2 = *(const bf16x8*)(g2 + c8 * 8);
      union { uint4 u; u16 s[8]; } o;
#pragma unroll
      for (int e = 0; e < 8; ++e) {
        float f = w0 * b2f((u16)v0[e]) + w1 * b2f((u16)v1[e]) +
                  w2 * b2f((u16)v2[e]);
        o.s[e] = f2b(f);
      }
      *(uint4*)(dst + c8 * 8) = o.u;
    }
    __syncthreads();
#pragma unroll
    for (int i = 0; i < 4; ++i)
#pragma unroll
      for (int reg = 0; reg < 4; ++reg) {
        int row = wm * 64 + i * 16 + q * 4 + reg;
#pragma unroll
        for (int j = 0; j < 4; ++j) {
          int col = wn * 64 + j * 16 + m;
          acc[i][j][reg] += b2f(smem[row * 128 + col]);
        }
      }
  }

  if (STATS) {
    int rep = blockIdx.x & (NREP - 1);
#pragma unroll
    for (int j = 0; j < 4; ++j) {
      float s = 0.0f, ss = 0.0f;
#pragma unroll
      for (int i = 0; i < 4; ++i)
#pragma unroll
        for (int reg = 0; reg < 4; ++reg) {
          float v = acc[i][j][reg];
          s += v;
          ss += v * v;
        }
      s += __shfl_down(s, 32); ss += __shfl_down(ss, 32);
      s += __shfl_down(s, 16); ss += __shfl_down(ss, 16);
      if (l < 16) {
        int c = o0 + wn * 64 + j * 16 + l;
        atomicAdd(&statsOut[rep * 512 + c], s);
        atomicAdd(&statsOut[rep * 512 + 256 + c], ss);
      }
    }
  }

#pragma unroll
  for (int i = 0; i < 4; ++i) {
    int gr = n0 + wm * 64 + i * 16 + q * 4;
#pragma unroll
    for (int reg = 0; reg < 4; ++reg) {
#pragma unroll
      for (int j = 0; j < 4; ++j) {
        int gc = o0 + wn * 64 + j * 16 + m;
        size_t off = (size_t)(gr + reg) * 256 + gc;
        if (OUTB)
          ((u16*)out)[off] = f2b(acc[i][j][reg]);
        else
          ((float*)out)[off] = acc[i][j][reg];
      }
    }
  }
}

// ---------------------------------------------------------------------------
// Kernel 6: BN2 + ReLU + transpose h2(bf16, B*N x 256) -> out fp32 (B,256,N).
// Reads finalized (collapsed) stats2.
// ---------------------------------------------------------------------------
__global__ __launch_bounds__(256) void bn2t_kernel(
    const u16* __restrict__ h2, const float* __restrict__ stats,
    const float* __restrict__ gamma, const float* __restrict__ beta,
    float* __restrict__ out) {
  __shared__ float tile[32][33];
  int tx = threadIdx.x & 31, ty = threadIdx.x >> 5;
  int n0 = blockIdx.x * 32, c0 = blockIdx.y * 32, b = blockIdx.z;
  int c = c0 + tx;
  float mean = stats[c] * INV_CNT;
  float var = stats[256 + c] * INV_CNT - mean * mean;
  float s = rsqrtf(var + EPSV) * gamma[c];
  float sh = beta[c] - mean * s;
#pragma unroll
  for (int i = 0; i < 4; ++i) {
    int n = n0 + ty + i * 8;
    float v = b2f(h2[((size_t)b * NN + n) * 256 + c]) * s + sh;
    tile[ty + i * 8][tx] = fmaxf(v, 0.0f);
  }
  __syncthreads();
#pragma unroll
  for (int i = 0; i < 4; ++i)
    out[((size_t)b * 256 + c0 + ty + i * 8) * NN + n0 + tx] = tile[tx][ty + i * 8];
}

// ---------------------------------------------------------------------------
// ws layout (bytes):
//   0        w3        786432
//   786432   i3        786432
//   1572864  stats1R   65536   (32 replicas x 512 floats)
//   1638400  stats2R   65536
//   1703936  stats2f   2048    (collapsed s2,q2)
//   1705984  W1b       196608
//   1902592  W2b       131072
//   2033664  p2t       8388608   \ pd(4.2MB)+pi(4.2MB) alias here during knn
//   10422272 p1t       16777216  / (dead before tcast overwrites)
//   27199488 G(bf16)   8388608
//   35588096 h2b       33554432  -> ends ~69.1 MB
// h1b (bf16) lives in d_out; gemm2 reads it (BN1 fused), bn2t overwrites.
// ---------------------------------------------------------------------------
extern "C" void kernel_launch(void* const* d_in, const int* in_sizes, int n_in,
                              void* d_out, int out_size, void* d_ws,
                              size_t ws_size, hipStream_t stream) {
  const float* xyz1    = (const float*)d_in[0];
  const float* xyz2    = (const float*)d_in[1];
  const float* points1 = (const float*)d_in[2];
  const float* points2 = (const float*)d_in[3];
  const float* W1      = (const float*)d_in[4];
  const float* gamma1  = (const float*)d_in[5];
  const float* beta1   = (const float*)d_in[6];
  const float* W2      = (const float*)d_in[7];
  const float* gamma2  = (const float*)d_in[8];
  const float* beta2   = (const float*)d_in[9];

  char* ws = (char*)d_ws;
  float* w3      = (float*)(ws + 0);
  int*   i3      = (int*)(ws + 786432);
  float* stats1R = (float*)(ws + 1572864);
  float* stats2R = (float*)(ws + 1638400);
  float* stats2f = (float*)(ws + 1703936);
  u16*   W1b     = (u16*)(ws + 1705984);
  u16*   W2b     = (u16*)(ws + 1902592);
  float* pd      = (float*)(ws + 2033664);
  int*   pi      = (int*)(ws + 2033664 + 4194304);
  u16*   p2t     = (u16*)(ws + 2033664);
  u16*   p1t     = (u16*)(ws + 10422272);
  u16*   G       = (u16*)(ws + 27199488);
  u16*   h2b     = (u16*)(ws + 35588096);
  u16*   h1b     = (u16*)d_out;
  float* out     = (float*)d_out;

  hipMemsetAsync(stats1R, 0, 131072, stream);  // both replica regions
  knn_kernel<<<512, 256, 0, stream>>>(xyz1, xyz2, pd, pi);
  knn_merge<<<256, 256, 0, stream>>>(pd, pi, w3, i3);
  cast_w_kernel<<<384, 256, 0, stream>>>(W1, W1b, 98304);
  cast_w_kernel<<<256, 256, 0, stream>>>(W2, W2b, 65536);
  tcast_kernel<<<dim3(32, 8, 16), 256, 0, stream>>>(points2, p2t, C2V, MM);
  tcast_kernel<<<dim3(128, 4, 16), 256, 0, stream>>>(points1, p1t, C1V, NN);
  // G = p2^T * W1[:, 0:256]^T (bf16 out), XCD-swizzled: batch b on XCD b/2
  gemm_mfma<256, 8, false, false, true, false><<<dim3(128, 2), 256, 0, stream>>>(
      p2t, 256, W1b, 384, G, nullptr, nullptr, nullptr, nullptr, nullptr,
      nullptr, nullptr);
  // h1 = p1t * W1[:, 256:384]^T + interp(G); stats1 replica atomics; bf16 out
  gemm_mfma<128, 32, true, true, true, false><<<dim3(512, 2), 256, 0, stream>>>(
      p1t, 128, W1b + 256, 384, h1b, G, w3, i3, stats1R, nullptr, nullptr,
      nullptr);
  // h2 = relu(BN1(h1)) * W2^T, BN1 replica-sum in preamble; stats2 atomics
  gemm_mfma<256, 0, false, true, true, true><<<dim3(512, 2), 256, 0, stream>>>(
      h1b, 256, W2b, 256, h2b, nullptr, nullptr, nullptr, stats2R, stats1R,
      gamma1, beta1);
  stats_finalize<<<1, 512, 0, stream>>>(stats2R, stats2f);
  bn2t_kernel<<<dim3(128, 8, 16), 256, 0, stream>>>(h2b, stats2f, gamma2,
                                                    beta2, out);
}

// Round 7
// 251.329 us; speedup vs baseline: 3.3667x; 1.0256x over previous
//
#include <hip/hip_runtime.h>

typedef unsigned short u16;
typedef unsigned int u32;

#define BB 16
#define NN 4096
#define MM 1024
#define C1V 128
#define C2V 256
#define O1 256
#define O2 256
#define EPSV 1e-5f
#define INV_CNT (1.0f/65536.0f)
#define NREP 32  // stats atomic replicas

typedef __attribute__((ext_vector_type(8))) short bf16x8;
typedef __attribute__((ext_vector_type(4))) float f32x4;

static __device__ __forceinline__ u16 f2b(float f) {
  u32 u = __float_as_uint(f);
  u32 r = (u + 0x7FFFu + ((u >> 16) & 1u)) >> 16;
  return (u16)r;
}
static __device__ __forceinline__ float b2f(u16 s) {
  return __uint_as_float(((u32)s) << 16);
}

#define GLD_LDS16(gp, lp)                                                      \
  __builtin_amdgcn_global_load_lds(                                            \
      (const __attribute__((address_space(1))) void*)(gp),                     \
      (__attribute__((address_space(3))) void*)(lp), 16, 0, 0)

// ---------------------------------------------------------------------------
// Kernel 1: 3-NN partials. Grid 512 = b(16) x qtile(8) x chunk(4).
// ---------------------------------------------------------------------------
__global__ __launch_bounds__(256) void knn_kernel(
    const float* __restrict__ xyz1, const float* __restrict__ xyz2,
    float* __restrict__ pd, int* __restrict__ pi) {
  __shared__ float4 cand[256];
  int bx = blockIdx.x;
  int c = bx & 3;
  int qt = (bx >> 2) & 7;
  int b = bx >> 5;
  int t = threadIdx.x;

  const float* x2b = xyz2 + b * 3 * MM;
  {
    float x = x2b[c * 256 + t];
    float y = x2b[MM + c * 256 + t];
    float z = x2b[2 * MM + c * 256 + t];
    cand[t] = make_float4(x, y, z, x * x + y * y + z * z);
  }
  __syncthreads();

  const float* x1b = xyz1 + b * 3 * NN;
  int n0 = qt * 512 + t;
  int n1 = n0 + 256;
  float px0 = x1b[n0], py0 = x1b[NN + n0], pz0 = x1b[2 * NN + n0];
  float px1 = x1b[n1], py1 = x1b[NN + n1], pz1 = x1b[2 * NN + n1];

  const float INF = 3.4e38f;
  float k00 = INF, k01 = INF, k02 = INF;
  float k10 = INF, k11 = INF, k12 = INF;
  int j00 = 0, j01 = 0, j02 = 0;
  int j10 = 0, j11 = 0, j12 = 0;

#pragma unroll 8
  for (int m = 0; m < 256; ++m) {
    float4 cd = cand[m];
    {
      float dot = fmaf(px0, cd.x, fmaf(py0, cd.y, pz0 * cd.z));
      float key = fmaf(-2.0f, dot, cd.w);
      bool c0 = key < k00, c1 = key < k01, c2 = key < k02;
      k02 = c1 ? k01 : (c2 ? key : k02);
      j02 = c1 ? j01 : (c2 ? m : j02);
      k01 = c0 ? k00 : (c1 ? key : k01);
      j01 = c0 ? j00 : (c1 ? m : j01);
      k00 = c0 ? key : k00;
      j00 = c0 ? m : j00;
    }
    {
      float dot = fmaf(px1, cd.x, fmaf(py1, cd.y, pz1 * cd.z));
      float key = fmaf(-2.0f, dot, cd.w);
      bool c0 = key < k10, c1 = key < k11, c2 = key < k12;
      k12 = c1 ? k11 : (c2 ? key : k12);
      j12 = c1 ? j11 : (c2 ? m : j12);
      k11 = c0 ? k10 : (c1 ? key : k11);
      j11 = c0 ? j10 : (c1 ? m : j11);
      k10 = c0 ? key : k10;
      j10 = c0 ? m : j10;
    }
  }

  float pn0 = px0 * px0 + py0 * py0 + pz0 * pz0;
  float pn1 = px1 * px1 + py1 * py1 + pz1 * pz1;
  int gq0 = b * NN + n0;
  int gq1 = b * NN + n1;
  int base = c << 8;
  ((float4*)pd)[(size_t)c * 65536 + gq0] =
      make_float4(fmaxf(k00 + pn0, 1e-10f), fmaxf(k01 + pn0, 1e-10f),
                  fmaxf(k02 + pn0, 1e-10f), 0.0f);
  ((int4*)pi)[(size_t)c * 65536 + gq0] =
      make_int4(base + j00, base + j01, base + j02, 0);
  ((float4*)pd)[(size_t)c * 65536 + gq1] =
      make_float4(fmaxf(k10 + pn1, 1e-10f), fmaxf(k11 + pn1, 1e-10f),
                  fmaxf(k12 + pn1, 1e-10f), 0.0f);
  ((int4*)pi)[(size_t)c * 65536 + gq1] =
      make_int4(base + j10, base + j11, base + j12, 0);
}

// ---------------------------------------------------------------------------
// Kernel 2: fp32 -> bf16 cast for both W1 (98304) and W2 (65536), one launch.
// ---------------------------------------------------------------------------
__global__ __launch_bounds__(256) void cast_w_kernel(
    const float* __restrict__ W1, const float* __restrict__ W2,
    u16* __restrict__ d1, u16* __restrict__ d2) {
  int i = blockIdx.x * 256 + threadIdx.x;
  if (i < 98304) d1[i] = f2b(W1[i]);
  else if (i < 163840) d2[i - 98304] = f2b(W2[i - 98304]);
}

// ---------------------------------------------------------------------------
// Kernel 3: transpose-cast (B, C, P) fp32 -> (B, P, C) bf16 via LDS tile.
// ---------------------------------------------------------------------------
__global__ __launch_bounds__(256) void tcast_kernel(
    const float* __restrict__ in, u16* __restrict__ out, int C, int P) {
  __shared__ float tile[32][33];
  int tx = threadIdx.x & 31, ty = threadIdx.x >> 5;
  int p0 = blockIdx.x * 32, c0 = blockIdx.y * 32, b = blockIdx.z;
  const float* ib = in + (size_t)b * C * P;
  u16* ob = out + (size_t)b * P * C;
#pragma unroll
  for (int i = 0; i < 4; ++i)
    tile[ty + i * 8][tx] = ib[(size_t)(c0 + ty + i * 8) * P + p0 + tx];
  __syncthreads();
#pragma unroll
  for (int i = 0; i < 4; ++i)
    ob[(size_t)(p0 + ty + i * 8) * C + c0 + tx] = f2b(tile[tx][ty + i * 8]);
}

// ---------------------------------------------------------------------------
// MFMA GEMM: 128x128 tile, 4 waves 2x2, 4x4 mfma_f32_16x16x32_bf16 each.
//   NTILES>0: XCD-aware row-swizzle (batches {2k,2k+1} -> XCD k).
//   INTERP : preamble merges 4-chunk knn partials (pd/pi) for this block's
//            rows; post-loop builds combined interp tile in LDS via bf16x8
//            gathers with XOR-swizzled chunks (conflict-free writes), then
//            per-lane C-layout add (swizzled readback).
//   STATS  : per-column sum/sumsq atomics into replica (blockIdx.x & 31).
//   OUTB   : bf16 store.   BNA: A-staging applies BN(sum of replicas)+ReLU.
// ---------------------------------------------------------------------------
template <int K, int NTILES, bool INTERP, bool STATS, bool OUTB, bool BNA>
__global__ __launch_bounds__(256) void gemm_mfma(
    const u16* __restrict__ A, int lda, const u16* __restrict__ B, int ldb,
    void* __restrict__ out, const u16* __restrict__ G,
    const float* __restrict__ pd, const int* __restrict__ pi,
    float* __restrict__ statsOut, const float* __restrict__ statsInR,
    const float* __restrict__ gamma, const float* __restrict__ beta) {
  __shared__ u16 smem[16384];  // K-loop: As[0,4096) Bs[4096,8192); interp: all
  __shared__ float wsh[128][3];
  __shared__ int ish[128][3];
  __shared__ float scA[256], shA[256];

  int t = threadIdx.x;
  int w = t >> 6, l = t & 63;
  int n0;
  if (NTILES > 0) {
    int p = blockIdx.x;
    int batch = ((p & 7) << 1) | ((p >> 3) & 1);
    int nt = p >> 4;
    n0 = (batch * NTILES + nt) * 128;
  } else {
    n0 = blockIdx.x * 128;
  }
  int o0 = blockIdx.y * 128;

  if (INTERP) {
    // in-block merge of the 4 knn chunk partials for rows n0..n0+127
    if (t < 128) {
      int gq = n0 + t;
      float4 d0 = ((const float4*)pd)[gq];
      int4 ii0 = ((const int4*)pi)[gq];
      float a0 = d0.x, a1 = d0.y, a2 = d0.z;
      int b0 = ii0.x, b1 = ii0.y, b2 = ii0.z;
#pragma unroll
      for (int c = 1; c < 4; ++c) {
        float4 dc = ((const float4*)pd)[(size_t)c * 65536 + gq];
        int4 ic = ((const int4*)pi)[(size_t)c * 65536 + gq];
        float kv[3] = {dc.x, dc.y, dc.z};
        int jv[3] = {ic.x, ic.y, ic.z};
#pragma unroll
        for (int j = 0; j < 3; ++j) {
          float key = kv[j];
          int idx = jv[j];
          bool c0 = key < a0, c1 = key < a1, c2 = key < a2;
          a2 = c1 ? a1 : (c2 ? key : a2);
          b2 = c1 ? b1 : (c2 ? idx : b2);
          a1 = c0 ? a0 : (c1 ? key : a1);
          b1 = c0 ? b0 : (c1 ? idx : b1);
          a0 = c0 ? key : a0;
          b0 = c0 ? idx : b0;
        }
      }
      float v0 = 1.0f / a0, v1 = 1.0f / a1, v2 = 1.0f / a2;
      float s = 1.0f / (v0 + v1 + v2);
      wsh[t][0] = v0 * s; wsh[t][1] = v1 * s; wsh[t][2] = v2 * s;
      ish[t][0] = b0;     ish[t][1] = b1;     ish[t][2] = b2;
    }
  }
  if (BNA) {
    float s = 0.0f, qq = 0.0f;
#pragma unroll
    for (int r = 0; r < NREP; ++r) {
      s += statsInR[r * 512 + t];
      qq += statsInR[r * 512 + 256 + t];
    }
    float mean = s * INV_CNT;
    float var = qq * INV_CNT - mean * mean;
    float sc = rsqrtf(var + EPSV) * gamma[t];
    scA[t] = sc;
    shA[t] = beta[t] - mean * sc;
  }

  int wm = w & 1, wn = w >> 1;
  int lr = l >> 2, lc = l & 3;  // staging: row-in-16, 16B chunk
  int q = l >> 4, m = l & 15;   // mfma lane decomposition

  f32x4 acc[4][4] = {};
  u16* As = smem;
  u16* Bs = smem + 4096;

  const u16* arow = A + (size_t)n0 * lda;
  const u16* brow = B + (size_t)o0 * ldb;

#pragma unroll
  for (int kt = 0; kt < K; kt += 32) {
    __syncthreads();
#pragma unroll
    for (int r = 0; r < 2; ++r) {
      int row = r * 64 + w * 16 + lr;
      if (BNA) {
        union { uint4 u; u16 s[8]; } v, o;
        v.u = *(const uint4*)(arow + (size_t)row * lda + kt + lc * 8);
        int cb = kt + lc * 8;
#pragma unroll
        for (int j = 0; j < 8; ++j) {
          float f = fmaf(b2f(v.s[j]), scA[cb + j], shA[cb + j]);
          o.s[j] = f2b(fmaxf(f, 0.0f));
        }
        *(uint4*)(As + row * 32 + lc * 8) = o.u;
      } else {
        GLD_LDS16(arow + (size_t)row * lda + kt + lc * 8, As + row * 32 + lc * 8);
      }
    }
#pragma unroll
    for (int r = 0; r < 2; ++r) {
      int row = r * 64 + w * 16 + lr;
      GLD_LDS16(brow + (size_t)row * ldb + kt + lc * 8, Bs + row * 32 + lc * 8);
    }
    __syncthreads();
    bf16x8 af[4], bf[4];
#pragma unroll
    for (int i = 0; i < 4; ++i)
      af[i] = *(const bf16x8*)(As + (wm * 64 + i * 16 + m) * 32 + q * 8);
#pragma unroll
    for (int j = 0; j < 4; ++j)
      bf[j] = *(const bf16x8*)(Bs + (wn * 64 + j * 16 + m) * 32 + q * 8);
#pragma unroll
    for (int i = 0; i < 4; ++i)
#pragma unroll
      for (int j = 0; j < 4; ++j)
        acc[i][j] =
            __builtin_amdgcn_mfma_f32_16x16x32_bf16(af[i], bf[j], acc[i][j], 0, 0, 0);
  }

  if (INTERP) {
    __syncthreads();  // As/Bs dead; reuse full smem as XOR-swizzled 128x128
    int b = n0 >> 12;
    int rl = t >> 1, half = t & 1, rx = rl & 7;
    float w0 = wsh[rl][0], w1 = wsh[rl][1], w2 = wsh[rl][2];
    const u16* g0 = G + ((size_t)(b * 1024 + ish[rl][0])) * 256 + o0 + half * 64;
    const u16* g1 = G + ((size_t)(b * 1024 + ish[rl][1])) * 256 + o0 + half * 64;
    const u16* g2 = G + ((size_t)(b * 1024 + ish[rl][2])) * 256 + o0 + half * 64;
#pragma unroll
    for (int c8 = 0; c8 < 8; ++c8) {
      bf16x8 v0 = *(const bf16x8*)(g0 + c8 * 8);
      bf16x8 v1 = *(const bf16x8*)(g1 + c8 * 8);
      bf16x8 v2 = *(const bf16x8*)(g2 + c8 * 8);
      union { uint4 u; u16 s[8]; } o;
#pragma unroll
      for (int e = 0; e < 8; ++e) {
        float f = w0 * b2f((u16)v0[e]) + w1 * b2f((u16)v1[e]) +
                  w2 * b2f((u16)v2[e]);
        o.s[e] = f2b(f);
      }
      int ch = (half * 8 + c8) ^ rx;  // XOR swizzle -> conflict-free banks
      *(uint4*)(smem + rl * 128 + ch * 8) = o.u;
    }
    __syncthreads();
#pragma unroll
    for (int i = 0; i < 4; ++i)
#pragma unroll
      for (int reg = 0; reg < 4; ++reg) {
        int row = wm * 64 + i * 16 + q * 4 + reg;
        int rxr = row & 7;
#pragma unroll
        for (int j = 0; j < 4; ++j) {
          int col = wn * 64 + j * 16 + m;
          int off = row * 128 + (((col >> 3) ^ rxr) << 3) + (col & 7);
          acc[i][j][reg] += b2f(smem[off]);
        }
      }
  }

  if (STATS) {
    int rep = blockIdx.x & (NREP - 1);
#pragma unroll
    for (int j = 0; j < 4; ++j) {
      float s = 0.0f, ss = 0.0f;
#pragma unroll
      for (int i = 0; i < 4; ++i)
#pragma unroll
        for (int reg = 0; reg < 4; ++reg) {
          float v = acc[i][j][reg];
          s += v;
          ss += v * v;
        }
      s += __shfl_down(s, 32); ss += __shfl_down(ss, 32);
      s += __shfl_down(s, 16); ss += __shfl_down(ss, 16);
      if (l < 16) {
        int c = o0 + wn * 64 + j * 16 + l;
        atomicAdd(&statsOut[rep * 512 + c], s);
        atomicAdd(&statsOut[rep * 512 + 256 + c], ss);
      }
    }
  }

#pragma unroll
  for (int i = 0; i < 4; ++i) {
    int gr = n0 + wm * 64 + i * 16 + q * 4;
#pragma unroll
    for (int reg = 0; reg < 4; ++reg) {
#pragma unroll
      for (int j = 0; j < 4; ++j) {
        int gc = o0 + wn * 64 + j * 16 + m;
        size_t off = (size_t)(gr + reg) * 256 + gc;
        if (OUTB)
          ((u16*)out)[off] = f2b(acc[i][j][reg]);
        else
          ((float*)out)[off] = acc[i][j][reg];
      }
    }
  }
}

// ---------------------------------------------------------------------------
// Kernel 6: BN2 + ReLU + transpose h2(bf16, B*N x 256) -> out fp32 (B,256,N).
// Collapses the NREP stats2 replicas for its 32 columns in the preamble.
// ---------------------------------------------------------------------------
__global__ __launch_bounds__(256) void bn2t_kernel(
    const u16* __restrict__ h2, const float* __restrict__ statsR,
    const float* __restrict__ gamma, const float* __restrict__ beta,
    float* __restrict__ out) {
  __shared__ float tile[32][33];
  __shared__ float sS[32], sH[32];
  int t = threadIdx.x;
  int tx = t & 31, ty = t >> 5;
  int n0 = blockIdx.x * 32, c0 = blockIdx.y * 32, b = blockIdx.z;
  if (t < 32) {
    int c = c0 + t;
    float s = 0.0f, qq = 0.0f;
#pragma unroll
    for (int r = 0; r < NREP; ++r) {
      s += statsR[r * 512 + c];
      qq += statsR[r * 512 + 256 + c];
    }
    float mean = s * INV_CNT;
    float var = qq * INV_CNT - mean * mean;
    float sc = rsqrtf(var + EPSV) * gamma[c];
    sS[t] = sc;
    sH[t] = beta[c] - mean * sc;
  }
  __syncthreads();
#pragma unroll
  for (int i = 0; i < 4; ++i) {
    int n = n0 + ty + i * 8;
    float v = b2f(h2[((size_t)b * NN + n) * 256 + c0 + tx]) * sS[tx] + sH[tx];
    tile[ty + i * 8][tx] = fmaxf(v, 0.0f);
  }
  __syncthreads();
#pragma unroll
  for (int i = 0; i < 4; ++i)
    out[((size_t)b * 256 + c0 + ty + i * 8) * NN + n0 + tx] = tile[tx][ty + i * 8];
}

// ---------------------------------------------------------------------------
// ws layout (bytes):
//   0        stats1R   65536   (32 replicas x 512 floats)
//   65536    stats2R   65536
//   131072   W1b       196608
//   327680   W2b       131072
//   458752   p2t       8388608
//   8847360  p1t       16777216
//   25624576 G(bf16)   8388608
//   34013184 h2b       33554432
//   67567616 pd        4194304   (knn partials, live until gemm1)
//   71761920 pi        4194304   -> ends ~76 MB
// h1b (bf16) lives in d_out; gemm2 reads it (BN1 fused), bn2t overwrites.
// ---------------------------------------------------------------------------
extern "C" void kernel_launch(void* const* d_in, const int* in_sizes, int n_in,
                              void* d_out, int out_size, void* d_ws,
                              size_t ws_size, hipStream_t stream) {
  const float* xyz1    = (const float*)d_in[0];
  const float* xyz2    = (const float*)d_in[1];
  const float* points1 = (const float*)d_in[2];
  const float* points2 = (const float*)d_in[3];
  const float* W1      = (const float*)d_in[4];
  const float* gamma1  = (const float*)d_in[5];
  const float* beta1   = (const float*)d_in[6];
  const float* W2      = (const float*)d_in[7];
  const float* gamma2  = (const float*)d_in[8];
  const float* beta2   = (const float*)d_in[9];

  char* ws = (char*)d_ws;
  float* stats1R = (float*)(ws + 0);
  float* stats2R = (float*)(ws + 65536);
  u16*   W1b     = (u16*)(ws + 131072);
  u16*   W2b     = (u16*)(ws + 327680);
  u16*   p2t     = (u16*)(ws + 458752);
  u16*   p1t     = (u16*)(ws + 8847360);
  u16*   G       = (u16*)(ws + 25624576);
  u16*   h2b     = (u16*)(ws + 34013184);
  float* pd      = (float*)(ws + 67567616);
  int*   pi      = (int*)(ws + 71761920);
  u16*   h1b     = (u16*)d_out;
  float* out     = (float*)d_out;

  hipMemsetAsync(stats1R, 0, 131072, stream);  // both replica regions
  knn_kernel<<<512, 256, 0, stream>>>(xyz1, xyz2, pd, pi);
  cast_w_kernel<<<640, 256, 0, stream>>>(W1, W2, W1b, W2b);
  tcast_kernel<<<dim3(32, 8, 16), 256, 0, stream>>>(points2, p2t, C2V, MM);
  tcast_kernel<<<dim3(128, 4, 16), 256, 0, stream>>>(points1, p1t, C1V, NN);
  // G = p2^T * W1[:, 0:256]^T (bf16 out), XCD-swizzled: batch b on XCD b/2
  gemm_mfma<256, 8, false, false, true, false><<<dim3(128, 2), 256, 0, stream>>>(
      p2t, 256, W1b, 384, G, nullptr, nullptr, nullptr, nullptr, nullptr,
      nullptr, nullptr);
  // h1 = p1t * W1[:, 256:384]^T + interp(G); merge in preamble; stats1 atomics
  gemm_mfma<128, 32, true, true, true, false><<<dim3(512, 2), 256, 0, stream>>>(
      p1t, 128, W1b + 256, 384, h1b, G, pd, pi, stats1R, nullptr, nullptr,
      nullptr);
  // h2 = relu(BN1(h1)) * W2^T, BN1 replica-sum in preamble; stats2 atomics
  gemm_mfma<256, 0, false, true, true, true><<<dim3(512, 2), 256, 0, stream>>>(
      h1b, 256, W2b, 256, h2b, nullptr, nullptr, nullptr, stats2R, stats1R,
      gamma1, beta1);
  bn2t_kernel<<<dim3(128, 8, 16), 256, 0, stream>>>(h2b, stats2R, gamma2,
                                                    beta2, out);
}

// Round 9
// 233.079 us; speedup vs baseline: 3.6303x; 1.0783x over previous
//
#include <hip/hip_runtime.h>

typedef unsigned short u16;
typedef unsigned int u32;

#define BB 16
#define NN 4096
#define MM 1024
#define C1V 128
#define C2V 256
#define O1 256
#define O2 256
#define EPSV 1e-5f
#define INV_CNT (1.0f/65536.0f)
#define NREP 32  // stats atomic replicas

typedef __attribute__((ext_vector_type(8))) short bf16x8;
typedef __attribute__((ext_vector_type(4))) float f32x4;

static __device__ __forceinline__ u16 f2b(float f) {
  u32 u = __float_as_uint(f);
  u32 r = (u + 0x7FFFu + ((u >> 16) & 1u)) >> 16;
  return (u16)r;
}
static __device__ __forceinline__ float b2f(u16 s) {
  return __uint_as_float(((u32)s) << 16);
}

#define GLD_LDS16(gp, lp)                                                      \
  __builtin_amdgcn_global_load_lds(                                            \
      (const __attribute__((address_space(1))) void*)(gp),                     \
      (__attribute__((address_space(3))) void*)(lp), 16, 0, 0)

// ---------------------------------------------------------------------------
// Mega-prep kernel: one dispatch for all independent preprocessing.
//   blocks [0,512)        : 3-NN partials (b x qtile x chunk)
//   blocks [512,1152)     : W1/W2 fp32->bf16 cast
//   blocks [1152,1184)    : zero the 128KB stats replica region
//   blocks [1184,5280)    : transpose-cast points2 -> p2t
//   blocks [5280,13472)   : transpose-cast points1 -> p1t
// ---------------------------------------------------------------------------
__device__ __forceinline__ void tcast_tile(const float* __restrict__ in,
                                           u16* __restrict__ out, int C, int P,
                                           int p0, int c0, int b,
                                           float (*tile)[33]) {
  int tx = threadIdx.x & 31, ty = threadIdx.x >> 5;
  const float* ib = in + (size_t)b * C * P;
  u16* ob = out + (size_t)b * P * C;
#pragma unroll
  for (int i = 0; i < 4; ++i)
    tile[ty + i * 8][tx] = ib[(size_t)(c0 + ty + i * 8) * P + p0 + tx];
  __syncthreads();
#pragma unroll
  for (int i = 0; i < 4; ++i)
    ob[(size_t)(p0 + ty + i * 8) * C + c0 + tx] = f2b(tile[tx][ty + i * 8]);
}

__global__ __launch_bounds__(256) void prep_kernel(
    const float* __restrict__ xyz1, const float* __restrict__ xyz2,
    float* __restrict__ pd, int* __restrict__ pi,
    const float* __restrict__ points1, const float* __restrict__ points2,
    u16* __restrict__ p1t, u16* __restrict__ p2t,
    const float* __restrict__ W1, const float* __restrict__ W2,
    u16* __restrict__ W1b, u16* __restrict__ W2b,
    float* __restrict__ statsZero) {
  __shared__ float4 cand[256];
  __shared__ float tile[32][33];
  int bx = blockIdx.x;
  int t = threadIdx.x;

  if (bx < 512) {
    // ---- 3-NN partials ----
    int c = bx & 3;
    int qt = (bx >> 2) & 7;
    int b = bx >> 5;
    const float* x2b = xyz2 + b * 3 * MM;
    {
      float x = x2b[c * 256 + t];
      float y = x2b[MM + c * 256 + t];
      float z = x2b[2 * MM + c * 256 + t];
      cand[t] = make_float4(x, y, z, x * x + y * y + z * z);
    }
    __syncthreads();
    const float* x1b = xyz1 + b * 3 * NN;
    int n0 = qt * 512 + t;
    int n1 = n0 + 256;
    float px0 = x1b[n0], py0 = x1b[NN + n0], pz0 = x1b[2 * NN + n0];
    float px1 = x1b[n1], py1 = x1b[NN + n1], pz1 = x1b[2 * NN + n1];
    const float INF = 3.4e38f;
    float k00 = INF, k01 = INF, k02 = INF;
    float k10 = INF, k11 = INF, k12 = INF;
    int j00 = 0, j01 = 0, j02 = 0;
    int j10 = 0, j11 = 0, j12 = 0;
#pragma unroll 8
    for (int m = 0; m < 256; ++m) {
      float4 cd = cand[m];
      {
        float dot = fmaf(px0, cd.x, fmaf(py0, cd.y, pz0 * cd.z));
        float key = fmaf(-2.0f, dot, cd.w);
        bool c0 = key < k00, c1 = key < k01, c2 = key < k02;
        k02 = c1 ? k01 : (c2 ? key : k02);
        j02 = c1 ? j01 : (c2 ? m : j02);
        k01 = c0 ? k00 : (c1 ? key : k01);
        j01 = c0 ? j00 : (c1 ? m : j01);
        k00 = c0 ? key : k00;
        j00 = c0 ? m : j00;
      }
      {
        float dot = fmaf(px1, cd.x, fmaf(py1, cd.y, pz1 * cd.z));
        float key = fmaf(-2.0f, dot, cd.w);
        bool c0 = key < k10, c1 = key < k11, c2 = key < k12;
        k12 = c1 ? k11 : (c2 ? key : k12);
        j12 = c1 ? j11 : (c2 ? m : j12);
        k11 = c0 ? k10 : (c1 ? key : k11);
        j11 = c0 ? j10 : (c1 ? m : j11);
        k10 = c0 ? key : k10;
        j10 = c0 ? m : j10;
      }
    }
    float pn0 = px0 * px0 + py0 * py0 + pz0 * pz0;
    float pn1 = px1 * px1 + py1 * py1 + pz1 * pz1;
    int gq0 = b * NN + n0;
    int gq1 = b * NN + n1;
    int base = c << 8;
    ((float4*)pd)[(size_t)c * 65536 + gq0] =
        make_float4(fmaxf(k00 + pn0, 1e-10f), fmaxf(k01 + pn0, 1e-10f),
                    fmaxf(k02 + pn0, 1e-10f), 0.0f);
    ((int4*)pi)[(size_t)c * 65536 + gq0] =
        make_int4(base + j00, base + j01, base + j02, 0);
    ((float4*)pd)[(size_t)c * 65536 + gq1] =
        make_float4(fmaxf(k10 + pn1, 1e-10f), fmaxf(k11 + pn1, 1e-10f),
                    fmaxf(k12 + pn1, 1e-10f), 0.0f);
    ((int4*)pi)[(size_t)c * 65536 + gq1] =
        make_int4(base + j10, base + j11, base + j12, 0);
  } else if (bx < 1152) {
    // ---- weight casts ----
    int i = (bx - 512) * 256 + t;
    if (i < 98304) W1b[i] = f2b(W1[i]);
    else if (i < 163840) W2b[i - 98304] = f2b(W2[i - 98304]);
  } else if (bx < 1184) {
    // ---- zero stats replicas: 32 blocks x 256 threads x 16B = 131072 B ----
    ((float4*)statsZero)[(bx - 1152) * 256 + t] =
        make_float4(0.f, 0.f, 0.f, 0.f);
  } else if (bx < 5280) {
    // ---- points2 transpose-cast: P=1024 (32 ptiles), C=256 (8 ctiles) ----
    int local = bx - 1184;
    int pt = local & 31, ct = (local >> 5) & 7, b = local >> 8;
    tcast_tile(points2, p2t, C2V, MM, pt * 32, ct * 32, b, tile);
  } else {
    // ---- points1 transpose-cast: P=4096 (128 ptiles), C=128 (4 ctiles) ----
    int local = bx - 5280;
    int pt = local & 127, ct = (local >> 7) & 3, b = local >> 9;
    tcast_tile(points1, p1t, C1V, NN, pt * 32, ct * 32, b, tile);
  }
}

// ---------------------------------------------------------------------------
// MFMA GEMM: 128x128 tile, 4 waves 2x2, 4x4 mfma_f32_16x16x32_bf16 each.
//   NTILES>0: XCD-aware row-swizzle (batches {2k,2k+1} -> XCD k).
//   INTERP : preamble merges 4-chunk knn partials (pd/pi) for this block's
//            rows; post-loop builds combined interp tile in LDS (XOR-swizzled
//            chunks, conflict-free) then per-lane C-layout add.
//   STATS  : per-column sum/sumsq atomics into replica (blockIdx.x & 31).
//   OUTB   : bf16 store via LDS bounce -> 8 dwordx4 stores/thread (coalesced).
//   BNA    : A-staging applies BN(sum of replicas)+ReLU.
// ---------------------------------------------------------------------------
template <int K, int NTILES, bool INTERP, bool STATS, bool OUTB, bool BNA>
__global__ __launch_bounds__(256) void gemm_mfma(
    const u16* __restrict__ A, int lda, const u16* __restrict__ B, int ldb,
    void* __restrict__ out, const u16* __restrict__ G,
    const float* __restrict__ pd, const int* __restrict__ pi,
    float* __restrict__ statsOut, const float* __restrict__ statsInR,
    const float* __restrict__ gamma, const float* __restrict__ beta) {
  __shared__ u16 smem[16384];  // K-loop: As|Bs; then interp tile; then C-tile
  __shared__ float wsh[128][3];
  __shared__ int ish[128][3];
  __shared__ float scA[256], shA[256];

  int t = threadIdx.x;
  int w = t >> 6, l = t & 63;
  int n0;
  if (NTILES > 0) {
    int p = blockIdx.x;
    int batch = ((p & 7) << 1) | ((p >> 3) & 1);
    int nt = p >> 4;
    n0 = (batch * NTILES + nt) * 128;
  } else {
    n0 = blockIdx.x * 128;
  }
  int o0 = blockIdx.y * 128;

  if (INTERP) {
    if (t < 128) {
      int gq = n0 + t;
      float4 d0 = ((const float4*)pd)[gq];
      int4 ii0 = ((const int4*)pi)[gq];
      float a0 = d0.x, a1 = d0.y, a2 = d0.z;
      int b0 = ii0.x, b1 = ii0.y, b2 = ii0.z;
#pragma unroll
      for (int c = 1; c < 4; ++c) {
        float4 dc = ((const float4*)pd)[(size_t)c * 65536 + gq];
        int4 ic = ((const int4*)pi)[(size_t)c * 65536 + gq];
        float kv[3] = {dc.x, dc.y, dc.z};
        int jv[3] = {ic.x, ic.y, ic.z};
#pragma unroll
        for (int j = 0; j < 3; ++j) {
          float key = kv[j];
          int idx = jv[j];
          bool c0 = key < a0, c1 = key < a1, c2 = key < a2;
          a2 = c1 ? a1 : (c2 ? key : a2);
          b2 = c1 ? b1 : (c2 ? idx : b2);
          a1 = c0 ? a0 : (c1 ? key : a1);
          b1 = c0 ? b0 : (c1 ? idx : b1);
          a0 = c0 ? key : a0;
          b0 = c0 ? idx : b0;
        }
      }
      float v0 = 1.0f / a0, v1 = 1.0f / a1, v2 = 1.0f / a2;
      float s = 1.0f / (v0 + v1 + v2);
      wsh[t][0] = v0 * s; wsh[t][1] = v1 * s; wsh[t][2] = v2 * s;
      ish[t][0] = b0;     ish[t][1] = b1;     ish[t][2] = b2;
    }
  }
  if (BNA) {
    float s = 0.0f, qq = 0.0f;
#pragma unroll
    for (int r = 0; r < NREP; ++r) {
      s += statsInR[r * 512 + t];
      qq += statsInR[r * 512 + 256 + t];
    }
    float mean = s * INV_CNT;
    float var = qq * INV_CNT - mean * mean;
    float sc = rsqrtf(var + EPSV) * gamma[t];
    scA[t] = sc;
    shA[t] = beta[t] - mean * sc;
  }

  int wm = w & 1, wn = w >> 1;
  int lr = l >> 2, lc = l & 3;  // staging: row-in-16, 16B chunk
  int q = l >> 4, m = l & 15;   // mfma lane decomposition

  f32x4 acc[4][4] = {};
  u16* As = smem;
  u16* Bs = smem + 4096;

  const u16* arow = A + (size_t)n0 * lda;
  const u16* brow = B + (size_t)o0 * ldb;

#pragma unroll
  for (int kt = 0; kt < K; kt += 32) {
    __syncthreads();
#pragma unroll
    for (int r = 0; r < 2; ++r) {
      int row = r * 64 + w * 16 + lr;
      if (BNA) {
        union { uint4 u; u16 s[8]; } v, o;
        v.u = *(const uint4*)(arow + (size_t)row * lda + kt + lc * 8);
        int cb = kt + lc * 8;
#pragma unroll
        for (int j = 0; j < 8; ++j) {
          float f = fmaf(b2f(v.s[j]), scA[cb + j], shA[cb + j]);
          o.s[j] = f2b(fmaxf(f, 0.0f));
        }
        *(uint4*)(As + row * 32 + lc * 8) = o.u;
      } else {
        GLD_LDS16(arow + (size_t)row * lda + kt + lc * 8, As + row * 32 + lc * 8);
      }
    }
#pragma unroll
    for (int r = 0; r < 2; ++r) {
      int row = r * 64 + w * 16 + lr;
      GLD_LDS16(brow + (size_t)row * ldb + kt + lc * 8, Bs + row * 32 + lc * 8);
    }
    __syncthreads();
    bf16x8 af[4], bf[4];
#pragma unroll
    for (int i = 0; i < 4; ++i)
      af[i] = *(const bf16x8*)(As + (wm * 64 + i * 16 + m) * 32 + q * 8);
#pragma unroll
    for (int j = 0; j < 4; ++j)
      bf[j] = *(const bf16x8*)(Bs + (wn * 64 + j * 16 + m) * 32 + q * 8);
#pragma unroll
    for (int i = 0; i < 4; ++i)
#pragma unroll
      for (int j = 0; j < 4; ++j)
        acc[i][j] =
            __builtin_amdgcn_mfma_f32_16x16x32_bf16(af[i], bf[j], acc[i][j], 0, 0, 0);
  }

  if (INTERP) {
    __syncthreads();  // As/Bs dead; reuse full smem as XOR-swizzled 128x128
    int b = n0 >> 12;
    int rl = t >> 1, half = t & 1, rx = rl & 7;
    float w0 = wsh[rl][0], w1 = wsh[rl][1], w2 = wsh[rl][2];
    const u16* g0 = G + ((size_t)(b * 1024 + ish[rl][0])) * 256 + o0 + half * 64;
    const u16* g1 = G + ((size_t)(b * 1024 + ish[rl][1])) * 256 + o0 + half * 64;
    const u16* g2 = G + ((size_t)(b * 1024 + ish[rl][2])) * 256 + o0 + half * 64;
#pragma unroll
    for (int c8 = 0; c8 < 8; ++c8) {
      bf16x8 v0 = *(const bf16x8*)(g0 + c8 * 8);
      bf16x8 v1 = *(const bf16x8*)(g1 + c8 * 8);
      bf16x8 v2 = *(const bf16x8*)(g2 + c8 * 8);
      union { uint4 u; u16 s[8]; } o;
#pragma unroll
      for (int e = 0; e < 8; ++e) {
        float f = w0 * b2f((u16)v0[e]) + w1 * b2f((u16)v1[e]) +
                  w2 * b2f((u16)v2[e]);
        o.s[e] = f2b(f);
      }
      int ch = (half * 8 + c8) ^ rx;  // XOR swizzle -> conflict-free banks
      *(uint4*)(smem + rl * 128 + ch * 8) = o.u;
    }
    __syncthreads();
#pragma unroll
    for (int i = 0; i < 4; ++i)
#pragma unroll
      for (int reg = 0; reg < 4; ++reg) {
        int row = wm * 64 + i * 16 + q * 4 + reg;
        int rxr = row & 7;
#pragma unroll
        for (int j = 0; j < 4; ++j) {
          int col = wn * 64 + j * 16 + m;
          int off = row * 128 + (((col >> 3) ^ rxr) << 3) + (col & 7);
          acc[i][j][reg] += b2f(smem[off]);
        }
      }
  }

  if (STATS) {
    int rep = blockIdx.x & (NREP - 1);
#pragma unroll
    for (int j = 0; j < 4; ++j) {
      float s = 0.0f, ss = 0.0f;
#pragma unroll
      for (int i = 0; i < 4; ++i)
#pragma unroll
        for (int reg = 0; reg < 4; ++reg) {
          float v = acc[i][j][reg];
          s += v;
          ss += v * v;
        }
      s += __shfl_down(s, 32); ss += __shfl_down(ss, 32);
      s += __shfl_down(s, 16); ss += __shfl_down(ss, 16);
      if (l < 16) {
        int c = o0 + wn * 64 + j * 16 + l;
        atomicAdd(&statsOut[rep * 512 + c], s);
        atomicAdd(&statsOut[rep * 512 + 256 + c], ss);
      }
    }
  }

  if (OUTB) {
    // C-write via LDS bounce: scalar C-layout writes, vector row readback.
    __syncthreads();  // smem free (post K-loop / post interp)
#pragma unroll
    for (int i = 0; i < 4; ++i)
#pragma unroll
      for (int reg = 0; reg < 4; ++reg) {
        int row = wm * 64 + i * 16 + q * 4 + reg;
#pragma unroll
        for (int j = 0; j < 4; ++j)
          smem[row * 128 + wn * 64 + j * 16 + m] = f2b(acc[i][j][reg]);
      }
    __syncthreads();
    u16* outp = (u16*)out;
    int rbase = w * 32 + (l >> 4);
    int seg = l & 15;
#pragma unroll
    for (int itr = 0; itr < 8; ++itr) {
      int row = rbase + itr * 4;
      uint4 v = *(const uint4*)(smem + row * 128 + seg * 8);
      *(uint4*)(outp + (size_t)(n0 + row) * 256 + o0 + seg * 8) = v;
    }
  } else {
#pragma unroll
    for (int i = 0; i < 4; ++i) {
      int gr = n0 + wm * 64 + i * 16 + q * 4;
#pragma unroll
      for (int reg = 0; reg < 4; ++reg)
#pragma unroll
        for (int j = 0; j < 4; ++j) {
          int gc = o0 + wn * 64 + j * 16 + m;
          ((float*)out)[(size_t)(gr + reg) * 256 + gc] = acc[i][j][reg];
        }
    }
  }
}

// ---------------------------------------------------------------------------
// BN2 + ReLU + transpose h2(bf16, B*N x 256) -> out fp32 (B,256,N).
// Collapses the NREP stats2 replicas for its 32 columns in the preamble.
// ---------------------------------------------------------------------------
__global__ __launch_bounds__(256) void bn2t_kernel(
    const u16* __restrict__ h2, const float* __restrict__ statsR,
    const float* __restrict__ gamma, const float* __restrict__ beta,
    float* __restrict__ out) {
  __shared__ float tile[32][33];
  __shared__ float sS[32], sH[32];
  int t = threadIdx.x;
  int tx = t & 31, ty = t >> 5;
  int n0 = blockIdx.x * 32, c0 = blockIdx.y * 32, b = blockIdx.z;
  if (t < 32) {
    int c = c0 + t;
    float s = 0.0f, qq = 0.0f;
#pragma unroll
    for (int r = 0; r < NREP; ++r) {
      s += statsR[r * 512 + c];
      qq += statsR[r * 512 + 256 + c];
    }
    float mean = s * INV_CNT;
    float var = qq * INV_CNT - mean * mean;
    float sc = rsqrtf(var + EPSV) * gamma[c];
    sS[t] = sc;
    sH[t] = beta[c] - mean * sc;
  }
  __syncthreads();
#pragma unroll
  for (int i = 0; i < 4; ++i) {
    int n = n0 + ty + i * 8;
    float v = b2f(h2[((size_t)b * NN + n) * 256 + c0 + tx]) * sS[tx] + sH[tx];
    tile[ty + i * 8][tx] = fmaxf(v, 0.0f);
  }
  __syncthreads();
#pragma unroll
  for (int i = 0; i < 4; ++i)
    out[((size_t)b * 256 + c0 + ty + i * 8) * NN + n0 + tx] = tile[tx][ty + i * 8];
}

// ---------------------------------------------------------------------------
// ws layout (bytes):
//   0        stats1R   65536   (32 replicas x 512 floats)
//   65536    stats2R   65536
//   131072   W1b       196608
//   327680   W2b       131072
//   458752   p2t       8388608
//   8847360  p1t       16777216
//   25624576 G(bf16)   8388608
//   34013184 h2b       33554432
//   67567616 pd        4194304
//   71761920 pi        4194304   -> ends ~76 MB
// h1b (bf16) lives in d_out; gemm2 reads it (BN1 fused), bn2t overwrites.
// ---------------------------------------------------------------------------
extern "C" void kernel_launch(void* const* d_in, const int* in_sizes, int n_in,
                              void* d_out, int out_size, void* d_ws,
                              size_t ws_size, hipStream_t stream) {
  const float* xyz1    = (const float*)d_in[0];
  const float* xyz2    = (const float*)d_in[1];
  const float* points1 = (const float*)d_in[2];
  const float* points2 = (const float*)d_in[3];
  const float* W1      = (const float*)d_in[4];
  const float* gamma1  = (const float*)d_in[5];
  const float* beta1   = (const float*)d_in[6];
  const float* W2      = (const float*)d_in[7];
  const float* gamma2  = (const float*)d_in[8];
  const float* beta2   = (const float*)d_in[9];

  char* ws = (char*)d_ws;
  float* stats1R = (float*)(ws + 0);
  float* stats2R = (float*)(ws + 65536);
  u16*   W1b     = (u16*)(ws + 131072);
  u16*   W2b     = (u16*)(ws + 327680);
  u16*   p2t     = (u16*)(ws + 458752);
  u16*   p1t     = (u16*)(ws + 8847360);
  u16*   G       = (u16*)(ws + 25624576);
  u16*   h2b     = (u16*)(ws + 34013184);
  float* pd      = (float*)(ws + 67567616);
  int*   pi      = (int*)(ws + 71761920);
  u16*   h1b     = (u16*)d_out;
  float* out     = (float*)d_out;

  // 1 dispatch: knn + W casts + stats zero + both transpose-casts
  prep_kernel<<<13472, 256, 0, stream>>>(xyz1, xyz2, pd, pi, points1, points2,
                                         p1t, p2t, W1, W2, W1b, W2b, stats1R);
  // G = p2^T * W1[:, 0:256]^T (bf16 out), XCD-swizzled: batch b on XCD b/2
  gemm_mfma<256, 8, false, false, true, false><<<dim3(128, 2), 256, 0, stream>>>(
      p2t, 256, W1b, 384, G, nullptr, nullptr, nullptr, nullptr, nullptr,
      nullptr, nullptr);
  // h1 = p1t * W1[:, 256:384]^T + interp(G); merge in preamble; stats1 atomics
  gemm_mfma<128, 32, true, true, true, false><<<dim3(512, 2), 256, 0, stream>>>(
      p1t, 128, W1b + 256, 384, h1b, G, pd, pi, stats1R, nullptr, nullptr,
      nullptr);
  // h2 = relu(BN1(h1)) * W2^T, BN1 replica-sum in preamble; stats2 atomics
  gemm_mfma<256, 0, false, true, true, true><<<dim3(512, 2), 256, 0, stream>>>(
      h1b, 256, W2b, 256, h2b, nullptr, nullptr, nullptr, stats2R, stats1R,
      gamma1, beta1);
  bn2t_kernel<<<dim3(128, 8, 16), 256, 0, stream>>>(h2b, stats2R, gamma2,
                                                    beta2, out);
}